// Round 13
// baseline (336.913 us; speedup 1.0000x reference)
//
#include <hip/hip_runtime.h>
#include <math.h>

#define NN 20000
#define HEADS 8
#define M_PAD 20096   // 157 * 128

typedef _Float16 f16;
typedef f16 f16x2  __attribute__((ext_vector_type(2)));
typedef f16 f16x4v __attribute__((ext_vector_type(4)));
typedef f16 f16x8v __attribute__((ext_vector_type(8)));
typedef float f32x4 __attribute__((ext_vector_type(4)));

// ---------- helpers ----------
__device__ __forceinline__ float lrelu(float x){ return x > 0.f ? x : 0.2f*x; }

// ---------- init: zero scratch + weight cvt fp32[K][N] -> f16[N][K] + wasT ----------
__global__ __launch_bounds__(256) void init_k(int* __restrict__ zbase, int zn,
        const float* __restrict__ W1, const float* __restrict__ W2, const float* __restrict__ W3,
        const float* __restrict__ Wg, const float* __restrict__ att_src, const float* __restrict__ att_dst,
        f16* __restrict__ wt1, f16* __restrict__ wt2, f16* __restrict__ wt3,
        f16* __restrict__ wasT)
{
    int t = blockIdx.x*256 + threadIdx.x;
    if (t < zn){ zbase[t] = 0; return; }
    t -= zn;
    if (t < 65536){ int k = t >> 8, n = t & 255; wt1[n*256 + k] = (f16)W1[t]; return; }
    t -= 65536;
    if (t < 65536){ int k = t >> 8, n = t & 255; wt2[n*256 + k] = (f16)W2[t]; return; }
    t -= 65536;
    if (t < 32768){ int k = t >> 7, n = t & 127; wt3[n*256 + k] = (f16)W3[t]; return; }
    t -= 32768;
    if (t < 8192){
        int r = t >> 7, k = t & 127;
        float s = 0.f;
        if (r < 16){
            const float* att = (r < 8) ? att_src : att_dst;
            int h = r & 7;
            const float* wg = Wg + (size_t)k*1024 + h*128;
            const float* at = att + h*128;
            for (int c = 0; c < 128; ++c) s = fmaf(wg[c], at[c], s);
        }
        wasT[r*128 + k] = (f16)s;
    }
}

// ---------- Wc = blockdiag(Wg) @ Wh1 folded:  wc_t[j][k] f16, biasc[j] = bg@Wh1 + bh1 ----------
__global__ __launch_bounds__(256) void wc_k(const float* __restrict__ Wg, const float* __restrict__ Wh1,
        const float* __restrict__ bg, const float* __restrict__ bh1,
        f16* __restrict__ wc_t, float* __restrict__ biasc)
{
    __shared__ float col[1024];   // Wh1[:, j]
    __shared__ float red[256];
    const int j = blockIdx.x, t = threadIdx.x;
    float bsum = 0.f;
    #pragma unroll
    for (int i = 0; i < 4; ++i){
        int kk = i*256 + t;
        float v = Wh1[(size_t)kk*256 + j];
        col[kk] = v;
        bsum = fmaf(bg[kk], v, bsum);
    }
    red[t] = bsum; __syncthreads();
    for (int off = 128; off; off >>= 1){
        if (t < off) red[t] += red[t+off];
        __syncthreads();
    }
    if (!t) biasc[j] = red[0] + bh1[j];
    #pragma unroll
    for (int i = 0; i < 4; ++i){
        int k = i*256 + t;
        int h = k >> 7, kk = k & 127;
        const float* wg = Wg + (size_t)kk*1024 + h*128;
        const float* cl = col + h*128;
        float s = 0.f;
        for (int c = 0; c < 128; c += 4){
            float4 wv = *(const float4*)(wg + c);
            s = fmaf(wv.x, cl[c],   s);
            s = fmaf(wv.y, cl[c+1], s);
            s = fmaf(wv.z, cl[c+2], s);
            s = fmaf(wv.w, cl[c+3], s);
        }
        wc_t[(size_t)j*1024 + k] = (f16)s;
    }
}

// ---------- CSR build ----------
__global__ __launch_bounds__(256) void hist_k(const int* __restrict__ dst, int* __restrict__ cnt, int E){
    int i = blockIdx.x*256 + threadIdx.x;
    if (i < E) atomicAdd(&cnt[dst[i]], 1);
}
__global__ __launch_bounds__(1024) void scan_k(const int* __restrict__ cnt, int* __restrict__ row_off,
                                               float* __restrict__ dinv){
    __shared__ int tot[1024];
    int t = threadIdx.x;
    const int CH = 20;
    int base = t*CH;
    int loc[CH]; int s = 0;
    #pragma unroll
    for (int i = 0; i < CH; ++i){
        int v = (base+i < NN) ? cnt[base+i] : 0;
        loc[i] = s; s += v;
    }
    tot[t] = s; __syncthreads();
    for (int off = 1; off < 1024; off <<= 1){
        int v = (t >= off) ? tot[t-off] : 0;
        __syncthreads();
        tot[t] += v;
        __syncthreads();
    }
    int pre = (t == 0) ? 0 : tot[t-1];
    #pragma unroll
    for (int i = 0; i < CH; ++i)
        if (base+i < NN){
            row_off[base+i] = pre + loc[i];
            dinv[base+i] = rsqrtf((float)cnt[base+i] + 1.f);
        }
    if (t == 1023) row_off[NN] = tot[1023];
}
__global__ __launch_bounds__(256) void scatter_k(const int* __restrict__ src, const int* __restrict__ dst,
        const int* __restrict__ row_off, int* __restrict__ cursor, int* __restrict__ src_sorted, int E){
    int i = blockIdx.x*256 + threadIdx.x;
    if (i >= E) return;
    int d = dst[i];
    int pos = row_off[d] + atomicAdd(&cursor[d], 1);
    src_sorted[pos] = src[i];
}

// ---------- fp16 MFMA GEMM (BN=64 fixed): C[M,N] = A[M,K] @ Bt[N,K]^T ----------
// BM=128, BK=64, 4 waves (2x2). Double-buffered LDS + named-reg prefetch (r11 spill
// lesson: no arrays/lambdas). XOR swizzle (16B chunks, chunk^=row&7) store+read.
// EPI: 0 = store f16 C; 2 = logit atomics (full K); 3 = attention-dot split store.
template<int EPI, bool A_F32, bool RELU, bool HAS_BIAS, int MINW>
__global__ __launch_bounds__(256, MINW) void gemm_f16_k(
        const void* __restrict__ Av, const f16* __restrict__ Bt,
        const float* __restrict__ bias, void* __restrict__ C,
        float* __restrict__ as_out, float* __restrict__ ad_out,
        const float* __restrict__ Wh2, float* __restrict__ logit,
        int M, int N, int K)
{
    constexpr int NJ = 2;                 // WN=32
    __shared__ __align__(16) f16 As[2][128*64];
    __shared__ __align__(16) f16 Bs[2][64*64];
    const int tid  = threadIdx.x;
    const int lane = tid & 63;
    const int wave = tid >> 6;
    const int wm = (wave >> 1) * 64, wn = (wave & 1) * 32;
    const int l15 = lane & 15, quad = lane >> 4;
    const int m0 = blockIdx.y * 128, n0 = blockIdx.x * 64;

    const int rs = tid >> 3;
    const int ce = (tid & 7) * 8;
    const int swst = ((rs & 7) << 3);
    const int swrd = ((l15 & 7) << 3);
    const f16*  Ah = (const f16*)Av;
    const float* Af = (const float*)Av;

    uint4 ra0, ra1, ra2, ra3, rb0, rb1;
    float4 rf00, rf01, rf10, rf11, rf20, rf21, rf30, rf31;

#define GEMM_ISSUE(k0)                                                                    \
    if (A_F32){                                                                           \
        int g0 = m0 + rs, g1 = g0 + 32, g2 = g0 + 64, g3 = g0 + 96;                       \
        if (g0 < M){ rf00 = *(const float4*)(Af + (size_t)g0*K + (k0) + ce);              \
                     rf01 = *(const float4*)(Af + (size_t)g0*K + (k0) + ce + 4); }        \
        else { rf00 = make_float4(0,0,0,0); rf01 = make_float4(0,0,0,0); }                \
        if (g1 < M){ rf10 = *(const float4*)(Af + (size_t)g1*K + (k0) + ce);              \
                     rf11 = *(const float4*)(Af + (size_t)g1*K + (k0) + ce + 4); }        \
        else { rf10 = make_float4(0,0,0,0); rf11 = make_float4(0,0,0,0); }                \
        if (g2 < M){ rf20 = *(const float4*)(Af + (size_t)g2*K + (k0) + ce);              \
                     rf21 = *(const float4*)(Af + (size_t)g2*K + (k0) + ce + 4); }        \
        else { rf20 = make_float4(0,0,0,0); rf21 = make_float4(0,0,0,0); }                \
        if (g3 < M){ rf30 = *(const float4*)(Af + (size_t)g3*K + (k0) + ce);              \
                     rf31 = *(const float4*)(Af + (size_t)g3*K + (k0) + ce + 4); }        \
        else { rf30 = make_float4(0,0,0,0); rf31 = make_float4(0,0,0,0); }                \
    } else {                                                                              \
        ra0 = *(const uint4*)(Ah + (size_t)(m0 + rs      )*K + (k0) + ce);                \
        ra1 = *(const uint4*)(Ah + (size_t)(m0 + rs + 32 )*K + (k0) + ce);                \
        ra2 = *(const uint4*)(Ah + (size_t)(m0 + rs + 64 )*K + (k0) + ce);                \
        ra3 = *(const uint4*)(Ah + (size_t)(m0 + rs + 96 )*K + (k0) + ce);                \
    }                                                                                     \
    rb0 = *(const uint4*)(Bt + (size_t)(n0 + rs     )*K + (k0) + ce);                     \
    rb1 = *(const uint4*)(Bt + (size_t)(n0 + rs + 32)*K + (k0) + ce);

#define GEMM_CVT(hv, lo, hi)                                                              \
    { hv[0]=(f16)lo.x; hv[1]=(f16)lo.y; hv[2]=(f16)lo.z; hv[3]=(f16)lo.w;                 \
      hv[4]=(f16)hi.x; hv[5]=(f16)hi.y; hv[6]=(f16)hi.z; hv[7]=(f16)hi.w; }

#define GEMM_WRITE(buf)                                                                   \
    if (A_F32){                                                                           \
        f16x8v h0, h1, h2, h3;                                                            \
        GEMM_CVT(h0, rf00, rf01) GEMM_CVT(h1, rf10, rf11)                                 \
        GEMM_CVT(h2, rf20, rf21) GEMM_CVT(h3, rf30, rf31)                                 \
        *(f16x8v*)&As[buf][(rs     )*64 + (ce ^ swst)] = h0;                              \
        *(f16x8v*)&As[buf][(rs + 32)*64 + (ce ^ swst)] = h1;                              \
        *(f16x8v*)&As[buf][(rs + 64)*64 + (ce ^ swst)] = h2;                              \
        *(f16x8v*)&As[buf][(rs + 96)*64 + (ce ^ swst)] = h3;                              \
    } else {                                                                              \
        *(uint4*)&As[buf][(rs     )*64 + (ce ^ swst)] = ra0;                              \
        *(uint4*)&As[buf][(rs + 32)*64 + (ce ^ swst)] = ra1;                              \
        *(uint4*)&As[buf][(rs + 64)*64 + (ce ^ swst)] = ra2;                              \
        *(uint4*)&As[buf][(rs + 96)*64 + (ce ^ swst)] = ra3;                              \
    }                                                                                     \
    *(uint4*)&Bs[buf][(rs     )*64 + (ce ^ swst)] = rb0;                                  \
    *(uint4*)&Bs[buf][(rs + 32)*64 + (ce ^ swst)] = rb1;

    GEMM_ISSUE(0)
    GEMM_WRITE(0)
    __syncthreads();

    f32x4 acc[4][NJ] = {};
    int cur = 0;
    for (int k0 = 64; k0 <= K; k0 += 64){
        const bool more = (k0 < K);
        if (more) { GEMM_ISSUE(k0) }
        #pragma unroll
        for (int ks = 0; ks < 2; ++ks){
            f16x8v af[4], bf[NJ];
            const int rc = (ks*32 + quad*8) ^ swrd;
            #pragma unroll
            for (int i = 0; i < 4; ++i)
                af[i] = *(const f16x8v*)&As[cur][(wm + i*16 + l15)*64 + rc];
            #pragma unroll
            for (int j = 0; j < NJ; ++j)
                bf[j] = *(const f16x8v*)&Bs[cur][(wn + j*16 + l15)*64 + rc];
            #pragma unroll
            for (int i = 0; i < 4; ++i)
                #pragma unroll
                for (int j = 0; j < NJ; ++j)
                    acc[i][j] = __builtin_amdgcn_mfma_f32_16x16x32_f16(af[i], bf[j], acc[i][j], 0, 0, 0);
        }
        if (more) { GEMM_WRITE(cur ^ 1) }
        __syncthreads();
        cur ^= 1;
    }
#undef GEMM_ISSUE
#undef GEMM_CVT
#undef GEMM_WRITE

    if (EPI == 2){
        float b4[NJ], w4[NJ];
        #pragma unroll
        for (int j = 0; j < NJ; ++j){
            int cg = n0 + wn + j*16 + l15;
            b4[j] = bias[cg]; w4[j] = Wh2[cg];
        }
        #pragma unroll
        for (int i = 0; i < 4; ++i)
            #pragma unroll
            for (int r = 0; r < 4; ++r){
                float ps = 0.f;
                #pragma unroll
                for (int j = 0; j < NJ; ++j){
                    float v = fmaxf(acc[i][j][r] + b4[j], 0.f);
                    ps = fmaf(v, w4[j], ps);
                }
                ps += __shfl_xor(ps, 1, 64); ps += __shfl_xor(ps, 2, 64);
                ps += __shfl_xor(ps, 4, 64); ps += __shfl_xor(ps, 8, 64);
                if (l15 == 0){
                    int row = m0 + wm + i*16 + quad*4 + r;
                    if (row < M) unsafeAtomicAdd(&logit[row], ps);
                }
            }
        return;
    }

    if (EPI == 3){
        #pragma unroll
        for (int i = 0; i < 4; ++i){
            int rb2 = m0 + wm + i*16 + quad*4;
            #pragma unroll
            for (int j = 0; j < NJ; ++j){
                int col = n0 + wn + j*16 + l15;
                if (col >= 16) continue;
                #pragma unroll
                for (int r = 0; r < 4; ++r){
                    int row = rb2 + r;
                    if (row >= M) continue;
                    float v = acc[i][j][r];
                    if (col < 8) as_out[row*8 + col] = v;
                    else         ad_out[row*8 + col - 8] = v;
                }
            }
        }
        return;
    }

    // store C (f16)
    #pragma unroll
    for (int i = 0; i < 4; ++i){
        int rb2 = m0 + wm + i*16 + quad*4;
        #pragma unroll
        for (int j = 0; j < NJ; ++j){
            int col = n0 + wn + j*16 + l15;
            float bv = HAS_BIAS ? bias[col] : 0.f;
            #pragma unroll
            for (int r = 0; r < 4; ++r){
                int row = rb2 + r;
                if (row >= M) continue;
                float v = acc[i][j][r] + bv;
                if (RELU) v = fmaxf(v, 0.f);
                ((f16*)C)[(size_t)row*N + col] = (f16)v;
            }
        }
    }
}

// ---------- GCN aggregation: 2 nodes/wave (half-wave each), wide per-lane loads ----------
// F=256: 32 lanes x f16x8 (16B/lane). F=128: 32 lanes x f16x4 (8B/lane).
// Half-wave edge loops diverge (exec-masked); cost = max(degA, degB) ~ deg.
template<int F>   // 256 or 128
__global__ __launch_bounds__(256) void gcn_agg_f16_k(const f16* __restrict__ h, const int* __restrict__ row_off,
        const int* __restrict__ srcs, const float* __restrict__ dinv, const float* __restrict__ bias,
        f16* __restrict__ out)
{
    int wv = (blockIdx.x*256 + threadIdx.x) >> 6;
    int lane = threadIdx.x & 63;
    int half = lane >> 5, l32 = lane & 31;
    int node = wv*2 + half;
    if (node >= NN) return;
    float di = dinv[node];
    int p = row_off[node], r1 = row_off[node+1];
    if (F == 256){
        f16x8v v = *(const f16x8v*)(h + (size_t)node*256 + l32*8);
        float c = di*di;
        float a[8];
        #pragma unroll
        for (int q = 0; q < 8; ++q) a[q] = (float)v[q]*c;
        for (; p+2 <= r1; p += 2){
            int s0 = srcs[p], s1 = srcs[p+1];
            float c0 = dinv[s0]*di, c1 = dinv[s1]*di;
            f16x8v u0 = *(const f16x8v*)(h + (size_t)s0*256 + l32*8);
            f16x8v u1 = *(const f16x8v*)(h + (size_t)s1*256 + l32*8);
            #pragma unroll
            for (int q = 0; q < 8; ++q)
                a[q] = fmaf((float)u1[q], c1, fmaf((float)u0[q], c0, a[q]));
        }
        for (; p < r1; ++p){
            int s0 = srcs[p];
            float c0 = dinv[s0]*di;
            f16x8v u0 = *(const f16x8v*)(h + (size_t)s0*256 + l32*8);
            #pragma unroll
            for (int q = 0; q < 8; ++q) a[q] = fmaf((float)u0[q], c0, a[q]);
        }
        float4 b0 = *(const float4*)(bias + l32*8);
        float4 b1 = *(const float4*)(bias + l32*8 + 4);
        f16x8v o;
        o[0]=(f16)fmaxf(a[0]+b0.x,0.f); o[1]=(f16)fmaxf(a[1]+b0.y,0.f);
        o[2]=(f16)fmaxf(a[2]+b0.z,0.f); o[3]=(f16)fmaxf(a[3]+b0.w,0.f);
        o[4]=(f16)fmaxf(a[4]+b1.x,0.f); o[5]=(f16)fmaxf(a[5]+b1.y,0.f);
        o[6]=(f16)fmaxf(a[6]+b1.z,0.f); o[7]=(f16)fmaxf(a[7]+b1.w,0.f);
        *(f16x8v*)(out + (size_t)node*256 + l32*8) = o;
    } else {
        f16x4v v = *(const f16x4v*)(h + (size_t)node*128 + l32*4);
        float c = di*di;
        float a[4];
        #pragma unroll
        for (int q = 0; q < 4; ++q) a[q] = (float)v[q]*c;
        for (; p+2 <= r1; p += 2){
            int s0 = srcs[p], s1 = srcs[p+1];
            float c0 = dinv[s0]*di, c1 = dinv[s1]*di;
            f16x4v u0 = *(const f16x4v*)(h + (size_t)s0*128 + l32*4);
            f16x4v u1 = *(const f16x4v*)(h + (size_t)s1*128 + l32*4);
            #pragma unroll
            for (int q = 0; q < 4; ++q)
                a[q] = fmaf((float)u1[q], c1, fmaf((float)u0[q], c0, a[q]));
        }
        for (; p < r1; ++p){
            int s0 = srcs[p];
            float c0 = dinv[s0]*di;
            f16x4v u0 = *(const f16x4v*)(h + (size_t)s0*128 + l32*4);
            #pragma unroll
            for (int q = 0; q < 4; ++q) a[q] = fmaf((float)u0[q], c0, a[q]);
        }
        float4 bv = *(const float4*)(bias + l32*4);
        f16x4v o;
        o[0]=(f16)fmaxf(a[0]+bv.x,0.f); o[1]=(f16)fmaxf(a[1]+bv.y,0.f);
        o[2]=(f16)fmaxf(a[2]+bv.z,0.f); o[3]=(f16)fmaxf(a[3]+bv.w,0.f);
        *(f16x4v*)(out + (size_t)node*128 + l32*4) = o;
    }
}

// ---------- GAT softmax over CSR (thread per (node,head), __expf) ----------
__global__ __launch_bounds__(256) void gat_soft_k(const int* __restrict__ row_off, const int* __restrict__ srcs,
        const float* __restrict__ a_s, const float* __restrict__ a_d,
        float* __restrict__ ex_sorted, float* __restrict__ alpha_self, float* __restrict__ inv_den)
{
    int t = blockIdx.x*256 + threadIdx.x;
    if (t >= NN*HEADS) return;
    int d = t >> 3, h = t & 7;
    float ad = a_d[t];
    float eself = lrelu(a_s[t] + ad);
    float m = eself;
    int r0 = row_off[d], r1 = row_off[d+1];
    for (int p = r0; p < r1; ++p){
        int s = srcs[p];
        m = fmaxf(m, lrelu(a_s[s*HEADS + h] + ad));
    }
    float den = __expf(eself - m);
    for (int p = r0; p < r1; ++p){
        int s = srcs[p];
        float x = __expf(lrelu(a_s[s*HEADS + h] + ad) - m);
        ex_sorted[(size_t)p*HEADS + h] = x;
        den += x;
    }
    float id = 1.f / den;
    alpha_self[t] = __expf(eself - m) * id;
    inv_den[t]    = id;
}

// ---------- GAT aggregation in fG-space: 2 nodes/wave, f16x4 (8B/lane) ----------
// agg[n, h*128 + c] = alpha_self[n,h]*fG[n,c] + sum_e alpha[e,h]*fG[src_e, c]
__global__ __launch_bounds__(256) void agg_k(const f16* __restrict__ fG, const int* __restrict__ row_off,
        const int* __restrict__ srcs, const float* __restrict__ exs, const float* __restrict__ aself,
        const float* __restrict__ idn, f16* __restrict__ agg)
{
    int wv = (blockIdx.x*256 + threadIdx.x) >> 6;
    int lane = threadIdx.x & 63;
    int half = lane >> 5, l32 = lane & 31;
    int node = wv*2 + half;
    if (node >= NN) return;
    f16x4v v = *(const f16x4v*)(fG + (size_t)node*128 + l32*4);
    float id[8], acc[8][4];
    #pragma unroll
    for (int h = 0; h < 8; ++h){
        float as = aself[node*8 + h];
        #pragma unroll
        for (int q = 0; q < 4; ++q) acc[h][q] = (float)v[q]*as;
        id[h] = idn[node*8 + h];
    }
    int p = row_off[node], r1 = row_off[node+1];
    for (; p < r1; ++p){
        int s0 = srcs[p];
        f16x4v u = *(const f16x4v*)(fG + (size_t)s0*128 + l32*4);
        float4 ea = *(const float4*)(exs + (size_t)p*8);
        float4 eb = *(const float4*)(exs + (size_t)p*8 + 4);
        float u0=(float)u[0], u1=(float)u[1], u2=(float)u[2], u3=(float)u[3];
        float e[8] = {ea.x,ea.y,ea.z,ea.w,eb.x,eb.y,eb.z,eb.w};
        #pragma unroll
        for (int h = 0; h < 8; ++h){
            float al = e[h]*id[h];
            acc[h][0] = fmaf(u0, al, acc[h][0]);
            acc[h][1] = fmaf(u1, al, acc[h][1]);
            acc[h][2] = fmaf(u2, al, acc[h][2]);
            acc[h][3] = fmaf(u3, al, acc[h][3]);
        }
    }
    #pragma unroll
    for (int h = 0; h < 8; ++h){
        f16x4v o;
        o[0]=(f16)acc[h][0]; o[1]=(f16)acc[h][1]; o[2]=(f16)acc[h][2]; o[3]=(f16)acc[h][3];
        *(f16x4v*)(agg + (size_t)node*1024 + h*128 + l32*4) = o;
    }
}

// ---------- head: sigmoid + global exp-sum (no max pass needed: w in (0,1)) ----------
__global__ __launch_bounds__(256) void head_sum_k(const float* __restrict__ logit, const float* __restrict__ bh2,
                                                  float* __restrict__ w, float* __restrict__ red){
    __shared__ float sm[256];
    int i = blockIdx.x*256 + threadIdx.x;
    float v = 0.f;
    if (i < NN){
        float s = 1.f / (1.f + expf(-(logit[i] + bh2[0])));
        w[i] = s;
        v = expf(s);
    }
    sm[threadIdx.x] = v; __syncthreads();
    for (int off = 128; off; off >>= 1){
        if (threadIdx.x < off) sm[threadIdx.x] += sm[threadIdx.x+off];
        __syncthreads();
    }
    if (!threadIdx.x) unsafeAtomicAdd(&red[0], sm[0]);
}
__global__ __launch_bounds__(256) void final_k(const float* __restrict__ w, const float* __restrict__ red,
                                               float* __restrict__ out){
    int i = blockIdx.x*256 + threadIdx.x;
    if (i >= NN) return;
    out[i] = expf(w[i]) / red[0];
}

// ---------- launch ----------
extern "C" void kernel_launch(void* const* d_in, const int* in_sizes, int n_in,
                              void* d_out, int out_size, void* d_ws, size_t ws_size,
                              hipStream_t stream) {
    const float* x   = (const float*)d_in[0];
    const int*   ei  = (const int*)  d_in[1];
    const float* W1  = (const float*)d_in[2];
    const float* b1  = (const float*)d_in[3];
    const float* W2  = (const float*)d_in[4];
    const float* b2  = (const float*)d_in[5];
    const float* W3  = (const float*)d_in[6];
    const float* b3  = (const float*)d_in[7];
    const float* Wg  = (const float*)d_in[8];
    const float* att_src = (const float*)d_in[9];
    const float* att_dst = (const float*)d_in[10];
    const float* bg  = (const float*)d_in[11];
    const float* Wh1 = (const float*)d_in[12];
    const float* bh1 = (const float*)d_in[13];
    const float* Wh2 = (const float*)d_in[14];
    const float* bh2 = (const float*)d_in[15];
    float* out = (float*)d_out;

    const int E = in_sizes[1] / 2;
    const int* src = ei;
    const int* dst = ei + E;

    float* ws = (float*)d_ws;
    size_t o = 0;
    auto alloc = [&](size_t nfloats){ float* p = ws + o; o += (nfloats + 3) & ~(size_t)3; return p; };
    // zero region: cnt, cursor, logit, red contiguous
    int* cnt    = (int*)alloc(NN);
    int* cursor = (int*)alloc(NN);
    float* logit= alloc(NN);
    float* red  = alloc(8);
    const int ZERO_N = 3*NN + 8;

    f16* wt1   = (f16*)alloc(65536/2);
    f16* wt2   = (f16*)alloc(65536/2);
    f16* wt3   = (f16*)alloc(32768/2);
    f16* wc_t  = (f16*)alloc(262144/2);          // [256][1024] f16
    f16* wasT  = (f16*)alloc(8192/2);            // [64][128] f16, rows 16+ zero
    float* biasc = alloc(256);
    f16* fH    = (f16*)alloc((size_t)M_PAD*256/2);
    f16* fG    = (f16*)alloc((size_t)M_PAD*256/2);
    f16* agg   = (f16*)alloc((size_t)M_PAD*1024/2);
    float* dinv = alloc(NN);
    float* a_s  = alloc((size_t)NN*HEADS);
    float* a_d  = alloc((size_t)NN*HEADS);
    float* aself= alloc((size_t)NN*HEADS);
    float* idn  = alloc((size_t)NN*HEADS);
    float* exs  = alloc((size_t)E*HEADS);
    float* wsig = alloc(NN);
    int* row_off= (int*)alloc(NN+1);
    int* src_srt= (int*)alloc(E);

    const int nb  = (NN + 255)/256;
    const int eb  = (E + 255)/256;
    const int nwb2 = (NN + 7)/8;   // 2 nodes/wave, 4 waves/block
    const dim3 blk(256);
    const int MT = M_PAD/128;   // 157

    // init (zero + weight cvt + wasT), Wc fold, CSR, dinv
    const int INIT_T = ZERO_N + 65536*2 + 32768 + 8192;
    init_k<<<(INIT_T + 255)/256, blk, 0, stream>>>(cnt, ZERO_N, W1, W2, W3, Wg, att_src, att_dst,
                                                   wt1, wt2, wt3, wasT);
    wc_k<<<256, blk, 0, stream>>>(Wg, Wh1, bg, bh1, wc_t, biasc);
    hist_k<<<eb, blk, 0, stream>>>(dst, cnt, E);
    scan_k<<<1, 1024, 0, stream>>>(cnt, row_off, dinv);
    scatter_k<<<eb, blk, 0, stream>>>(src, dst, row_off, cursor, src_srt, E);

    // GCN 1: A = x (fp32, read directly)  [4x157 blocks, dbuf prefetch]
    gemm_f16_k<0,true,false,false,3><<<dim3(4, MT), blk, 0, stream>>>(
        x, wt1, nullptr, fH, nullptr, nullptr, nullptr, nullptr, NN, 256, 256);
    gcn_agg_f16_k<256><<<nwb2, blk, 0, stream>>>(fH, row_off, src_srt, dinv, b1, fG);
    // GCN 2
    gemm_f16_k<0,false,false,false,3><<<dim3(4, MT), blk, 0, stream>>>(
        fG, wt2, nullptr, fH, nullptr, nullptr, nullptr, nullptr, NN, 256, 256);
    gcn_agg_f16_k<256><<<nwb2, blk, 0, stream>>>(fH, row_off, src_srt, dinv, b2, fG);
    // GCN 3 (N=128)
    gemm_f16_k<0,false,false,false,3><<<dim3(2, MT), blk, 0, stream>>>(
        fG, wt3, nullptr, fH, nullptr, nullptr, nullptr, nullptr, NN, 128, 256);
    gcn_agg_f16_k<128><<<nwb2, blk, 0, stream>>>(fH, row_off, src_srt, dinv, b3, fG);

    // GAT attention dots: a_sd = fG @ wasT^T via MFMA (EPI=3), M=20000, N=64(16 used), K=128
    gemm_f16_k<3,false,false,false,3><<<dim3(1, MT), blk, 0, stream>>>(
        fG, wasT, nullptr, nullptr, a_s, a_d, nullptr, nullptr, NN, 64, 128);
    // split softmax (exp once per (node,head) thread) + aggregation (reads exs weights)
    gat_soft_k<<<(NN*HEADS)/256, blk, 0, stream>>>(row_off, src_srt, a_s, a_d, exs, aself, idn);
    agg_k<<<nwb2, blk, 0, stream>>>(fG, row_off, src_srt, exs, aself, idn, agg);

    // head: z = relu(agg @ Wc + biasc), logit = z @ Wh2  [EPI=2: 628 blocks, full K=1024]
    gemm_f16_k<2,false,true,true,3><<<dim3(4, MT), blk, 0, stream>>>(
        agg, wc_t, biasc, nullptr, nullptr, nullptr, Wh2, logit, NN, 256, 1024);

    // sigmoid + global softmax (no max pass: w bounded in (0,1))
    head_sum_k<<<nb, blk, 0, stream>>>(logit, bh2, wsig, red);
    final_k<<<nb, blk, 0, stream>>>(wsig, red, out);
}

// Round 14
// 336.083 us; speedup vs baseline: 1.0025x; 1.0025x over previous
//
#include <hip/hip_runtime.h>
#include <math.h>

#define NN 20000
#define HEADS 8
#define M_PAD 20096   // 157 * 128

typedef _Float16 f16;
typedef f16 f16x2  __attribute__((ext_vector_type(2)));
typedef f16 f16x4v __attribute__((ext_vector_type(4)));
typedef f16 f16x8v __attribute__((ext_vector_type(8)));
typedef float f32x4 __attribute__((ext_vector_type(4)));

// ---------- helpers ----------
__device__ __forceinline__ float lrelu(float x){ return x > 0.f ? x : 0.2f*x; }

// ---------- init: zero scratch + weight cvt fp32[K][N] -> f16[N][K] + wasT ----------
__global__ __launch_bounds__(256) void init_k(int* __restrict__ zbase, int zn,
        const float* __restrict__ W1, const float* __restrict__ W2, const float* __restrict__ W3,
        const float* __restrict__ Wg, const float* __restrict__ att_src, const float* __restrict__ att_dst,
        f16* __restrict__ wt1, f16* __restrict__ wt2, f16* __restrict__ wt3,
        f16* __restrict__ wasT)
{
    int t = blockIdx.x*256 + threadIdx.x;
    if (t < zn){ zbase[t] = 0; return; }
    t -= zn;
    if (t < 65536){ int k = t >> 8, n = t & 255; wt1[n*256 + k] = (f16)W1[t]; return; }
    t -= 65536;
    if (t < 65536){ int k = t >> 8, n = t & 255; wt2[n*256 + k] = (f16)W2[t]; return; }
    t -= 65536;
    if (t < 32768){ int k = t >> 7, n = t & 127; wt3[n*256 + k] = (f16)W3[t]; return; }
    t -= 32768;
    if (t < 8192){
        int r = t >> 7, k = t & 127;
        float s = 0.f;
        if (r < 16){
            const float* att = (r < 8) ? att_src : att_dst;
            int h = r & 7;
            const float* wg = Wg + (size_t)k*1024 + h*128;
            const float* at = att + h*128;
            for (int c = 0; c < 128; ++c) s = fmaf(wg[c], at[c], s);
        }
        wasT[r*128 + k] = (f16)s;
    }
}

// ---------- Wc = blockdiag(Wg) @ Wh1 folded:  wc_t[j][k] f16, biasc[j] = bg@Wh1 + bh1 ----------
__global__ __launch_bounds__(256) void wc_k(const float* __restrict__ Wg, const float* __restrict__ Wh1,
        const float* __restrict__ bg, const float* __restrict__ bh1,
        f16* __restrict__ wc_t, float* __restrict__ biasc)
{
    __shared__ float col[1024];   // Wh1[:, j]
    __shared__ float red[256];
    const int j = blockIdx.x, t = threadIdx.x;
    float bsum = 0.f;
    #pragma unroll
    for (int i = 0; i < 4; ++i){
        int kk = i*256 + t;
        float v = Wh1[(size_t)kk*256 + j];
        col[kk] = v;
        bsum = fmaf(bg[kk], v, bsum);
    }
    red[t] = bsum; __syncthreads();
    for (int off = 128; off; off >>= 1){
        if (t < off) red[t] += red[t+off];
        __syncthreads();
    }
    if (!t) biasc[j] = red[0] + bh1[j];
    #pragma unroll
    for (int i = 0; i < 4; ++i){
        int k = i*256 + t;
        int h = k >> 7, kk = k & 127;
        const float* wg = Wg + (size_t)kk*1024 + h*128;
        const float* cl = col + h*128;
        float s = 0.f;
        for (int c = 0; c < 128; c += 4){
            float4 wv = *(const float4*)(wg + c);
            s = fmaf(wv.x, cl[c],   s);
            s = fmaf(wv.y, cl[c+1], s);
            s = fmaf(wv.z, cl[c+2], s);
            s = fmaf(wv.w, cl[c+3], s);
        }
        wc_t[(size_t)j*1024 + k] = (f16)s;
    }
}

// ---------- CSR build ----------
__global__ __launch_bounds__(256) void hist_k(const int* __restrict__ dst, int* __restrict__ cnt, int E){
    int i = blockIdx.x*256 + threadIdx.x;
    if (i < E) atomicAdd(&cnt[dst[i]], 1);
}
__global__ __launch_bounds__(1024) void scan_k(const int* __restrict__ cnt, int* __restrict__ row_off,
                                               float* __restrict__ dinv){
    __shared__ int tot[1024];
    int t = threadIdx.x;
    const int CH = 20;
    int base = t*CH;
    int loc[CH]; int s = 0;
    #pragma unroll
    for (int i = 0; i < CH; ++i){
        int v = (base+i < NN) ? cnt[base+i] : 0;
        loc[i] = s; s += v;
    }
    tot[t] = s; __syncthreads();
    for (int off = 1; off < 1024; off <<= 1){
        int v = (t >= off) ? tot[t-off] : 0;
        __syncthreads();
        tot[t] += v;
        __syncthreads();
    }
    int pre = (t == 0) ? 0 : tot[t-1];
    #pragma unroll
    for (int i = 0; i < CH; ++i)
        if (base+i < NN){
            row_off[base+i] = pre + loc[i];
            dinv[base+i] = rsqrtf((float)cnt[base+i] + 1.f);
        }
    if (t == 1023) row_off[NN] = tot[1023];
}
__global__ __launch_bounds__(256) void scatter_k(const int* __restrict__ src, const int* __restrict__ dst,
        const int* __restrict__ row_off, int* __restrict__ cursor, int* __restrict__ src_sorted, int E){
    int i = blockIdx.x*256 + threadIdx.x;
    if (i >= E) return;
    int d = dst[i];
    int pos = row_off[d] + atomicAdd(&cursor[d], 1);
    src_sorted[pos] = src[i];
}

// ---------- fp16 MFMA GEMM (BN=64 fixed): C[M,N] = A[M,K] @ Bt[N,K]^T ----------
// BM=128, BK=64, 4 waves (2x2). Double-buffered LDS + named-reg prefetch (r11 spill
// lesson: no arrays/lambdas). XOR swizzle (16B chunks, chunk^=row&7) store+read.
// EPI: 0 = store f16 C; 2 = logit atomics (full K); 3 = attention-dot split store.
template<int EPI, bool A_F32, bool RELU, bool HAS_BIAS, int MINW>
__global__ __launch_bounds__(256, MINW) void gemm_f16_k(
        const void* __restrict__ Av, const f16* __restrict__ Bt,
        const float* __restrict__ bias, void* __restrict__ C,
        float* __restrict__ as_out, float* __restrict__ ad_out,
        const float* __restrict__ Wh2, float* __restrict__ logit,
        int M, int N, int K)
{
    constexpr int NJ = 2;                 // WN=32
    __shared__ __align__(16) f16 As[2][128*64];
    __shared__ __align__(16) f16 Bs[2][64*64];
    const int tid  = threadIdx.x;
    const int lane = tid & 63;
    const int wave = tid >> 6;
    const int wm = (wave >> 1) * 64, wn = (wave & 1) * 32;
    const int l15 = lane & 15, quad = lane >> 4;
    const int m0 = blockIdx.y * 128, n0 = blockIdx.x * 64;

    const int rs = tid >> 3;
    const int ce = (tid & 7) * 8;
    const int swst = ((rs & 7) << 3);
    const int swrd = ((l15 & 7) << 3);
    const f16*  Ah = (const f16*)Av;
    const float* Af = (const float*)Av;

    uint4 ra0, ra1, ra2, ra3, rb0, rb1;
    float4 rf00, rf01, rf10, rf11, rf20, rf21, rf30, rf31;

#define GEMM_ISSUE(k0)                                                                    \
    if (A_F32){                                                                           \
        int g0 = m0 + rs, g1 = g0 + 32, g2 = g0 + 64, g3 = g0 + 96;                       \
        if (g0 < M){ rf00 = *(const float4*)(Af + (size_t)g0*K + (k0) + ce);              \
                     rf01 = *(const float4*)(Af + (size_t)g0*K + (k0) + ce + 4); }        \
        else { rf00 = make_float4(0,0,0,0); rf01 = make_float4(0,0,0,0); }                \
        if (g1 < M){ rf10 = *(const float4*)(Af + (size_t)g1*K + (k0) + ce);              \
                     rf11 = *(const float4*)(Af + (size_t)g1*K + (k0) + ce + 4); }        \
        else { rf10 = make_float4(0,0,0,0); rf11 = make_float4(0,0,0,0); }                \
        if (g2 < M){ rf20 = *(const float4*)(Af + (size_t)g2*K + (k0) + ce);              \
                     rf21 = *(const float4*)(Af + (size_t)g2*K + (k0) + ce + 4); }        \
        else { rf20 = make_float4(0,0,0,0); rf21 = make_float4(0,0,0,0); }                \
        if (g3 < M){ rf30 = *(const float4*)(Af + (size_t)g3*K + (k0) + ce);              \
                     rf31 = *(const float4*)(Af + (size_t)g3*K + (k0) + ce + 4); }        \
        else { rf30 = make_float4(0,0,0,0); rf31 = make_float4(0,0,0,0); }                \
    } else {                                                                              \
        ra0 = *(const uint4*)(Ah + (size_t)(m0 + rs      )*K + (k0) + ce);                \
        ra1 = *(const uint4*)(Ah + (size_t)(m0 + rs + 32 )*K + (k0) + ce);                \
        ra2 = *(const uint4*)(Ah + (size_t)(m0 + rs + 64 )*K + (k0) + ce);                \
        ra3 = *(const uint4*)(Ah + (size_t)(m0 + rs + 96 )*K + (k0) + ce);                \
    }                                                                                     \
    rb0 = *(const uint4*)(Bt + (size_t)(n0 + rs     )*K + (k0) + ce);                     \
    rb1 = *(const uint4*)(Bt + (size_t)(n0 + rs + 32)*K + (k0) + ce);

#define GEMM_CVT(hv, lo, hi)                                                              \
    { hv[0]=(f16)lo.x; hv[1]=(f16)lo.y; hv[2]=(f16)lo.z; hv[3]=(f16)lo.w;                 \
      hv[4]=(f16)hi.x; hv[5]=(f16)hi.y; hv[6]=(f16)hi.z; hv[7]=(f16)hi.w; }

#define GEMM_WRITE(buf)                                                                   \
    if (A_F32){                                                                           \
        f16x8v h0, h1, h2, h3;                                                            \
        GEMM_CVT(h0, rf00, rf01) GEMM_CVT(h1, rf10, rf11)                                 \
        GEMM_CVT(h2, rf20, rf21) GEMM_CVT(h3, rf30, rf31)                                 \
        *(f16x8v*)&As[buf][(rs     )*64 + (ce ^ swst)] = h0;                              \
        *(f16x8v*)&As[buf][(rs + 32)*64 + (ce ^ swst)] = h1;                              \
        *(f16x8v*)&As[buf][(rs + 64)*64 + (ce ^ swst)] = h2;                              \
        *(f16x8v*)&As[buf][(rs + 96)*64 + (ce ^ swst)] = h3;                              \
    } else {                                                                              \
        *(uint4*)&As[buf][(rs     )*64 + (ce ^ swst)] = ra0;                              \
        *(uint4*)&As[buf][(rs + 32)*64 + (ce ^ swst)] = ra1;                              \
        *(uint4*)&As[buf][(rs + 64)*64 + (ce ^ swst)] = ra2;                              \
        *(uint4*)&As[buf][(rs + 96)*64 + (ce ^ swst)] = ra3;                              \
    }                                                                                     \
    *(uint4*)&Bs[buf][(rs     )*64 + (ce ^ swst)] = rb0;                                  \
    *(uint4*)&Bs[buf][(rs + 32)*64 + (ce ^ swst)] = rb1;

    GEMM_ISSUE(0)
    GEMM_WRITE(0)
    __syncthreads();

    f32x4 acc[4][NJ] = {};
    int cur = 0;
    for (int k0 = 64; k0 <= K; k0 += 64){
        const bool more = (k0 < K);
        if (more) { GEMM_ISSUE(k0) }
        #pragma unroll
        for (int ks = 0; ks < 2; ++ks){
            f16x8v af[4], bf[NJ];
            const int rc = (ks*32 + quad*8) ^ swrd;
            #pragma unroll
            for (int i = 0; i < 4; ++i)
                af[i] = *(const f16x8v*)&As[cur][(wm + i*16 + l15)*64 + rc];
            #pragma unroll
            for (int j = 0; j < NJ; ++j)
                bf[j] = *(const f16x8v*)&Bs[cur][(wn + j*16 + l15)*64 + rc];
            #pragma unroll
            for (int i = 0; i < 4; ++i)
                #pragma unroll
                for (int j = 0; j < NJ; ++j)
                    acc[i][j] = __builtin_amdgcn_mfma_f32_16x16x32_f16(af[i], bf[j], acc[i][j], 0, 0, 0);
        }
        if (more) { GEMM_WRITE(cur ^ 1) }
        __syncthreads();
        cur ^= 1;
    }
#undef GEMM_ISSUE
#undef GEMM_CVT
#undef GEMM_WRITE

    if (EPI == 2){
        float b4[NJ], w4[NJ];
        #pragma unroll
        for (int j = 0; j < NJ; ++j){
            int cg = n0 + wn + j*16 + l15;
            b4[j] = bias[cg]; w4[j] = Wh2[cg];
        }
        #pragma unroll
        for (int i = 0; i < 4; ++i)
            #pragma unroll
            for (int r = 0; r < 4; ++r){
                float ps = 0.f;
                #pragma unroll
                for (int j = 0; j < NJ; ++j){
                    float v = fmaxf(acc[i][j][r] + b4[j], 0.f);
                    ps = fmaf(v, w4[j], ps);
                }
                ps += __shfl_xor(ps, 1, 64); ps += __shfl_xor(ps, 2, 64);
                ps += __shfl_xor(ps, 4, 64); ps += __shfl_xor(ps, 8, 64);
                if (l15 == 0){
                    int row = m0 + wm + i*16 + quad*4 + r;
                    if (row < M) unsafeAtomicAdd(&logit[row], ps);
                }
            }
        return;
    }

    if (EPI == 3){
        #pragma unroll
        for (int i = 0; i < 4; ++i){
            int rb2 = m0 + wm + i*16 + quad*4;
            #pragma unroll
            for (int j = 0; j < NJ; ++j){
                int col = n0 + wn + j*16 + l15;
                if (col >= 16) continue;
                #pragma unroll
                for (int r = 0; r < 4; ++r){
                    int row = rb2 + r;
                    if (row >= M) continue;
                    float v = acc[i][j][r];
                    if (col < 8) as_out[row*8 + col] = v;
                    else         ad_out[row*8 + col - 8] = v;
                }
            }
        }
        return;
    }

    // store C (f16)
    #pragma unroll
    for (int i = 0; i < 4; ++i){
        int rb2 = m0 + wm + i*16 + quad*4;
        #pragma unroll
        for (int j = 0; j < NJ; ++j){
            int col = n0 + wn + j*16 + l15;
            float bv = HAS_BIAS ? bias[col] : 0.f;
            #pragma unroll
            for (int r = 0; r < 4; ++r){
                int row = rb2 + r;
                if (row >= M) continue;
                float v = acc[i][j][r] + bv;
                if (RELU) v = fmaxf(v, 0.f);
                ((f16*)C)[(size_t)row*N + col] = (f16)v;
            }
        }
    }
}

// ---------- GCN aggregation (r12 form: 1 node/wave, 4-edge unroll) ----------
template<int F>   // 256 or 128
__global__ __launch_bounds__(256) void gcn_agg_f16_k(const f16* __restrict__ h, const int* __restrict__ row_off,
        const int* __restrict__ srcs, const float* __restrict__ dinv, const float* __restrict__ bias,
        f16* __restrict__ out)
{
    int wv = (blockIdx.x*256 + threadIdx.x) >> 6;
    int lane = threadIdx.x & 63;
    if (wv >= NN) return;
    float di = dinv[wv];
    int p = row_off[wv], r1 = row_off[wv+1];
    if (F == 256){
        f16x4v v = *(const f16x4v*)(h + (size_t)wv*256 + lane*4);
        float c = di*di;
        float a0 = (float)v[0]*c, a1 = (float)v[1]*c, a2 = (float)v[2]*c, a3 = (float)v[3]*c;
        for (; p+4 <= r1; p += 4){
            int s0 = srcs[p], s1 = srcs[p+1], s2 = srcs[p+2], s3 = srcs[p+3];
            float c0 = dinv[s0]*di, c1 = dinv[s1]*di, c2 = dinv[s2]*di, c3 = dinv[s3]*di;
            f16x4v u0 = *(const f16x4v*)(h + (size_t)s0*256 + lane*4);
            f16x4v u1 = *(const f16x4v*)(h + (size_t)s1*256 + lane*4);
            f16x4v u2 = *(const f16x4v*)(h + (size_t)s2*256 + lane*4);
            f16x4v u3 = *(const f16x4v*)(h + (size_t)s3*256 + lane*4);
            a0 = fmaf((float)u3[0], c3, fmaf((float)u2[0], c2, fmaf((float)u1[0], c1, fmaf((float)u0[0], c0, a0))));
            a1 = fmaf((float)u3[1], c3, fmaf((float)u2[1], c2, fmaf((float)u1[1], c1, fmaf((float)u0[1], c0, a1))));
            a2 = fmaf((float)u3[2], c3, fmaf((float)u2[2], c2, fmaf((float)u1[2], c1, fmaf((float)u0[2], c0, a2))));
            a3 = fmaf((float)u3[3], c3, fmaf((float)u2[3], c2, fmaf((float)u1[3], c1, fmaf((float)u0[3], c0, a3))));
        }
        for (; p < r1; ++p){
            int s0 = srcs[p];
            float c0 = dinv[s0]*di;
            f16x4v u0 = *(const f16x4v*)(h + (size_t)s0*256 + lane*4);
            a0 = fmaf((float)u0[0], c0, a0); a1 = fmaf((float)u0[1], c0, a1);
            a2 = fmaf((float)u0[2], c0, a2); a3 = fmaf((float)u0[3], c0, a3);
        }
        float4 bv = *(const float4*)(bias + lane*4);
        f16x4v o;
        o[0] = (f16)fmaxf(a0 + bv.x, 0.f); o[1] = (f16)fmaxf(a1 + bv.y, 0.f);
        o[2] = (f16)fmaxf(a2 + bv.z, 0.f); o[3] = (f16)fmaxf(a3 + bv.w, 0.f);
        *(f16x4v*)(out + (size_t)wv*256 + lane*4) = o;
    } else {
        f16x2 v = *(const f16x2*)(h + (size_t)wv*128 + lane*2);
        float c = di*di;
        float a0 = (float)v[0]*c, a1 = (float)v[1]*c;
        for (; p+4 <= r1; p += 4){
            int s0 = srcs[p], s1 = srcs[p+1], s2 = srcs[p+2], s3 = srcs[p+3];
            float c0 = dinv[s0]*di, c1 = dinv[s1]*di, c2 = dinv[s2]*di, c3 = dinv[s3]*di;
            f16x2 u0 = *(const f16x2*)(h + (size_t)s0*128 + lane*2);
            f16x2 u1 = *(const f16x2*)(h + (size_t)s1*128 + lane*2);
            f16x2 u2 = *(const f16x2*)(h + (size_t)s2*128 + lane*2);
            f16x2 u3 = *(const f16x2*)(h + (size_t)s3*128 + lane*2);
            a0 = fmaf((float)u3[0], c3, fmaf((float)u2[0], c2, fmaf((float)u1[0], c1, fmaf((float)u0[0], c0, a0))));
            a1 = fmaf((float)u3[1], c3, fmaf((float)u2[1], c2, fmaf((float)u1[1], c1, fmaf((float)u0[1], c0, a1))));
        }
        for (; p < r1; ++p){
            int s0 = srcs[p];
            float c0 = dinv[s0]*di;
            f16x2 u0 = *(const f16x2*)(h + (size_t)s0*128 + lane*2);
            a0 = fmaf((float)u0[0], c0, a0); a1 = fmaf((float)u0[1], c0, a1);
        }
        float2 bv = *(const float2*)(bias + lane*2);
        f16x2 o;
        o[0] = (f16)fmaxf(a0 + bv.x, 0.f); o[1] = (f16)fmaxf(a1 + bv.y, 0.f);
        *(f16x2*)(out + (size_t)wv*128 + lane*2) = o;
    }
}

// ---------- GAT softmax over CSR (thread per (node,head), __expf) ----------
__global__ __launch_bounds__(256) void gat_soft_k(const int* __restrict__ row_off, const int* __restrict__ srcs,
        const float* __restrict__ a_s, const float* __restrict__ a_d,
        float* __restrict__ ex_sorted, float* __restrict__ alpha_self, float* __restrict__ inv_den)
{
    int t = blockIdx.x*256 + threadIdx.x;
    if (t >= NN*HEADS) return;
    int d = t >> 3, h = t & 7;
    float ad = a_d[t];
    float eself = lrelu(a_s[t] + ad);
    float m = eself;
    int r0 = row_off[d], r1 = row_off[d+1];
    for (int p = r0; p < r1; ++p){
        int s = srcs[p];
        m = fmaxf(m, lrelu(a_s[s*HEADS + h] + ad));
    }
    float den = __expf(eself - m);
    for (int p = r0; p < r1; ++p){
        int s = srcs[p];
        float x = __expf(lrelu(a_s[s*HEADS + h] + ad) - m);
        ex_sorted[(size_t)p*HEADS + h] = x;
        den += x;
    }
    float id = 1.f / den;
    alpha_self[t] = __expf(eself - m) * id;
    inv_den[t]    = id;
}

// ---------- GAT aggregation: 1 node/wave, EVEN/ODD edge split across half-waves ----------
// Lanes 0-31 handle even edges, 32-63 odd edges of the SAME node (no inter-node
// divergence; serial edge chain halved). Each half-wave loads the full 256B row
// (f16x4/lane). Cross-half reduce via one shfl_xor(32) per accumulator at the end.
__global__ __launch_bounds__(256) void agg_k(const f16* __restrict__ fG, const int* __restrict__ row_off,
        const int* __restrict__ srcs, const float* __restrict__ exs, const float* __restrict__ aself,
        const float* __restrict__ idn, f16* __restrict__ agg)
{
    int wv = (blockIdx.x*256 + threadIdx.x) >> 6;
    int lane = threadIdx.x & 63;
    int half = lane >> 5, l32 = lane & 31;
    if (wv >= NN) return;
    f16x4v v = *(const f16x4v*)(fG + (size_t)wv*128 + l32*4);
    float id[8], acc[8][4];
    #pragma unroll
    for (int h = 0; h < 8; ++h){
        float as = (half == 0) ? aself[wv*8 + h] : 0.f;   // self term counted once
        #pragma unroll
        for (int q = 0; q < 4; ++q) acc[h][q] = (float)v[q]*as;
        id[h] = idn[wv*8 + h];
    }
    int r0 = row_off[wv], r1 = row_off[wv+1];
    for (int p = r0 + half; p < r1; p += 2){
        int s0 = srcs[p];
        f16x4v u = *(const f16x4v*)(fG + (size_t)s0*128 + l32*4);
        float4 ea = *(const float4*)(exs + (size_t)p*8);
        float4 eb = *(const float4*)(exs + (size_t)p*8 + 4);
        float u0=(float)u[0], u1=(float)u[1], u2=(float)u[2], u3=(float)u[3];
        float e[8] = {ea.x,ea.y,ea.z,ea.w,eb.x,eb.y,eb.z,eb.w};
        #pragma unroll
        for (int h = 0; h < 8; ++h){
            float al = e[h]*id[h];
            acc[h][0] = fmaf(u0, al, acc[h][0]);
            acc[h][1] = fmaf(u1, al, acc[h][1]);
            acc[h][2] = fmaf(u2, al, acc[h][2]);
            acc[h][3] = fmaf(u3, al, acc[h][3]);
        }
    }
    // cross-half reduction: lane l and l^32 hold partial sums of the same 4 cols
    #pragma unroll
    for (int h = 0; h < 8; ++h){
        #pragma unroll
        for (int q = 0; q < 4; ++q)
            acc[h][q] += __shfl_xor(acc[h][q], 32, 64);
    }
    if (half == 0){
        #pragma unroll
        for (int h = 0; h < 8; ++h){
            f16x4v o;
            o[0]=(f16)acc[h][0]; o[1]=(f16)acc[h][1]; o[2]=(f16)acc[h][2]; o[3]=(f16)acc[h][3];
            *(f16x4v*)(agg + (size_t)wv*1024 + h*128 + l32*4) = o;
        }
    }
}

// ---------- head: sigmoid + global exp-sum (no max pass needed: w in (0,1)) ----------
__global__ __launch_bounds__(256) void head_sum_k(const float* __restrict__ logit, const float* __restrict__ bh2,
                                                  float* __restrict__ w, float* __restrict__ red){
    __shared__ float sm[256];
    int i = blockIdx.x*256 + threadIdx.x;
    float v = 0.f;
    if (i < NN){
        float s = 1.f / (1.f + expf(-(logit[i] + bh2[0])));
        w[i] = s;
        v = expf(s);
    }
    sm[threadIdx.x] = v; __syncthreads();
    for (int off = 128; off; off >>= 1){
        if (threadIdx.x < off) sm[threadIdx.x] += sm[threadIdx.x+off];
        __syncthreads();
    }
    if (!threadIdx.x) unsafeAtomicAdd(&red[0], sm[0]);
}
__global__ __launch_bounds__(256) void final_k(const float* __restrict__ w, const float* __restrict__ red,
                                               float* __restrict__ out){
    int i = blockIdx.x*256 + threadIdx.x;
    if (i >= NN) return;
    out[i] = expf(w[i]) / red[0];
}

// ---------- launch ----------
extern "C" void kernel_launch(void* const* d_in, const int* in_sizes, int n_in,
                              void* d_out, int out_size, void* d_ws, size_t ws_size,
                              hipStream_t stream) {
    const float* x   = (const float*)d_in[0];
    const int*   ei  = (const int*)  d_in[1];
    const float* W1  = (const float*)d_in[2];
    const float* b1  = (const float*)d_in[3];
    const float* W2  = (const float*)d_in[4];
    const float* b2  = (const float*)d_in[5];
    const float* W3  = (const float*)d_in[6];
    const float* b3  = (const float*)d_in[7];
    const float* Wg  = (const float*)d_in[8];
    const float* att_src = (const float*)d_in[9];
    const float* att_dst = (const float*)d_in[10];
    const float* bg  = (const float*)d_in[11];
    const float* Wh1 = (const float*)d_in[12];
    const float* bh1 = (const float*)d_in[13];
    const float* Wh2 = (const float*)d_in[14];
    const float* bh2 = (const float*)d_in[15];
    float* out = (float*)d_out;

    const int E = in_sizes[1] / 2;
    const int* src = ei;
    const int* dst = ei + E;

    float* ws = (float*)d_ws;
    size_t o = 0;
    auto alloc = [&](size_t nfloats){ float* p = ws + o; o += (nfloats + 3) & ~(size_t)3; return p; };
    // zero region: cnt, cursor, logit, red contiguous
    int* cnt    = (int*)alloc(NN);
    int* cursor = (int*)alloc(NN);
    float* logit= alloc(NN);
    float* red  = alloc(8);
    const int ZERO_N = 3*NN + 8;

    f16* wt1   = (f16*)alloc(65536/2);
    f16* wt2   = (f16*)alloc(65536/2);
    f16* wt3   = (f16*)alloc(32768/2);
    f16* wc_t  = (f16*)alloc(262144/2);          // [256][1024] f16
    f16* wasT  = (f16*)alloc(8192/2);            // [64][128] f16, rows 16+ zero
    float* biasc = alloc(256);
    f16* fH    = (f16*)alloc((size_t)M_PAD*256/2);
    f16* fG    = (f16*)alloc((size_t)M_PAD*256/2);
    f16* agg   = (f16*)alloc((size_t)M_PAD*1024/2);
    float* dinv = alloc(NN);
    float* a_s  = alloc((size_t)NN*HEADS);
    float* a_d  = alloc((size_t)NN*HEADS);
    float* aself= alloc((size_t)NN*HEADS);
    float* idn  = alloc((size_t)NN*HEADS);
    float* exs  = alloc((size_t)E*HEADS);
    float* wsig = alloc(NN);
    int* row_off= (int*)alloc(NN+1);
    int* src_srt= (int*)alloc(E);

    const int nb  = (NN + 255)/256;
    const int eb  = (E + 255)/256;
    const int nwb = (NN + 3)/4;    // 1 node/wave, 4 waves/block
    const dim3 blk(256);
    const int MT = M_PAD/128;   // 157

    // init (zero + weight cvt + wasT), Wc fold, CSR, dinv
    const int INIT_T = ZERO_N + 65536*2 + 32768 + 8192;
    init_k<<<(INIT_T + 255)/256, blk, 0, stream>>>(cnt, ZERO_N, W1, W2, W3, Wg, att_src, att_dst,
                                                   wt1, wt2, wt3, wasT);
    wc_k<<<256, blk, 0, stream>>>(Wg, Wh1, bg, bh1, wc_t, biasc);
    hist_k<<<eb, blk, 0, stream>>>(dst, cnt, E);
    scan_k<<<1, 1024, 0, stream>>>(cnt, row_off, dinv);
    scatter_k<<<eb, blk, 0, stream>>>(src, dst, row_off, cursor, src_srt, E);

    // GCN 1: A = x (fp32, read directly)  [4x157 blocks, dbuf prefetch]
    gemm_f16_k<0,true,false,false,3><<<dim3(4, MT), blk, 0, stream>>>(
        x, wt1, nullptr, fH, nullptr, nullptr, nullptr, nullptr, NN, 256, 256);
    gcn_agg_f16_k<256><<<nwb, blk, 0, stream>>>(fH, row_off, src_srt, dinv, b1, fG);
    // GCN 2
    gemm_f16_k<0,false,false,false,3><<<dim3(4, MT), blk, 0, stream>>>(
        fG, wt2, nullptr, fH, nullptr, nullptr, nullptr, nullptr, NN, 256, 256);
    gcn_agg_f16_k<256><<<nwb, blk, 0, stream>>>(fH, row_off, src_srt, dinv, b2, fG);
    // GCN 3 (N=128)
    gemm_f16_k<0,false,false,false,3><<<dim3(2, MT), blk, 0, stream>>>(
        fG, wt3, nullptr, fH, nullptr, nullptr, nullptr, nullptr, NN, 128, 256);
    gcn_agg_f16_k<128><<<nwb, blk, 0, stream>>>(fH, row_off, src_srt, dinv, b3, fG);

    // GAT attention dots: a_sd = fG @ wasT^T via MFMA (EPI=3), M=20000, N=64(16 used), K=128
    gemm_f16_k<3,false,false,false,3><<<dim3(1, MT), blk, 0, stream>>>(
        fG, wasT, nullptr, nullptr, a_s, a_d, nullptr, nullptr, NN, 64, 128);
    // split softmax (exp once per (node,head) thread) + aggregation (reads exs weights)
    gat_soft_k<<<(NN*HEADS)/256, blk, 0, stream>>>(row_off, src_srt, a_s, a_d, exs, aself, idn);
    agg_k<<<nwb, blk, 0, stream>>>(fG, row_off, src_srt, exs, aself, idn, agg);

    // head: z = relu(agg @ Wc + biasc), logit = z @ Wh2  [EPI=2: 628 blocks, full K=1024]
    gemm_f16_k<2,false,true,true,3><<<dim3(4, MT), blk, 0, stream>>>(
        agg, wc_t, biasc, nullptr, nullptr, nullptr, Wh2, logit, NN, 256, 1024);

    // sigmoid + global softmax (no max pass: w bounded in (0,1))
    head_sum_k<<<nb, blk, 0, stream>>>(logit, bh2, wsig, red);
    final_k<<<nb, blk, 0, stream>>>(wsig, red, out);
}

// Round 15
// 333.987 us; speedup vs baseline: 1.0088x; 1.0063x over previous
//
#include <hip/hip_runtime.h>
#include <math.h>

#define NN 20000
#define HEADS 8
#define M_PAD 20096   // 157 * 128

typedef _Float16 f16;
typedef f16 f16x2  __attribute__((ext_vector_type(2)));
typedef f16 f16x4v __attribute__((ext_vector_type(4)));
typedef f16 f16x8v __attribute__((ext_vector_type(8)));
typedef float f32x4 __attribute__((ext_vector_type(4)));

// ---------- helpers ----------
__device__ __forceinline__ float lrelu(float x){ return x > 0.f ? x : 0.2f*x; }

// ---------- init: zero scratch + weight cvt fp32[K][N] -> f16[N][K] + wasT ----------
__global__ __launch_bounds__(256) void init_k(int* __restrict__ zbase, int zn,
        const float* __restrict__ W1, const float* __restrict__ W2, const float* __restrict__ W3,
        const float* __restrict__ Wg, const float* __restrict__ att_src, const float* __restrict__ att_dst,
        f16* __restrict__ wt1, f16* __restrict__ wt2, f16* __restrict__ wt3,
        f16* __restrict__ wasT)
{
    int t = blockIdx.x*256 + threadIdx.x;
    if (t < zn){ zbase[t] = 0; return; }
    t -= zn;
    if (t < 65536){ int k = t >> 8, n = t & 255; wt1[n*256 + k] = (f16)W1[t]; return; }
    t -= 65536;
    if (t < 65536){ int k = t >> 8, n = t & 255; wt2[n*256 + k] = (f16)W2[t]; return; }
    t -= 65536;
    if (t < 32768){ int k = t >> 7, n = t & 127; wt3[n*256 + k] = (f16)W3[t]; return; }
    t -= 32768;
    if (t < 8192){
        int r = t >> 7, k = t & 127;
        float s = 0.f;
        if (r < 16){
            const float* att = (r < 8) ? att_src : att_dst;
            int h = r & 7;
            const float* wg = Wg + (size_t)k*1024 + h*128;
            const float* at = att + h*128;
            for (int c = 0; c < 128; ++c) s = fmaf(wg[c], at[c], s);
        }
        wasT[r*128 + k] = (f16)s;
    }
}

// ---------- Wc = blockdiag(Wg) @ Wh1 folded:  wc_t[j][k] f16, biasc[j] = bg@Wh1 + bh1 ----------
__global__ __launch_bounds__(256) void wc_k(const float* __restrict__ Wg, const float* __restrict__ Wh1,
        const float* __restrict__ bg, const float* __restrict__ bh1,
        f16* __restrict__ wc_t, float* __restrict__ biasc)
{
    __shared__ float col[1024];   // Wh1[:, j]
    __shared__ float red[256];
    const int j = blockIdx.x, t = threadIdx.x;
    float bsum = 0.f;
    #pragma unroll
    for (int i = 0; i < 4; ++i){
        int kk = i*256 + t;
        float v = Wh1[(size_t)kk*256 + j];
        col[kk] = v;
        bsum = fmaf(bg[kk], v, bsum);
    }
    red[t] = bsum; __syncthreads();
    for (int off = 128; off; off >>= 1){
        if (t < off) red[t] += red[t+off];
        __syncthreads();
    }
    if (!t) biasc[j] = red[0] + bh1[j];
    #pragma unroll
    for (int i = 0; i < 4; ++i){
        int k = i*256 + t;
        int h = k >> 7, kk = k & 127;
        const float* wg = Wg + (size_t)kk*1024 + h*128;
        const float* cl = col + h*128;
        float s = 0.f;
        for (int c = 0; c < 128; c += 4){
            float4 wv = *(const float4*)(wg + c);
            s = fmaf(wv.x, cl[c],   s);
            s = fmaf(wv.y, cl[c+1], s);
            s = fmaf(wv.z, cl[c+2], s);
            s = fmaf(wv.w, cl[c+3], s);
        }
        wc_t[(size_t)j*1024 + k] = (f16)s;
    }
}

// ---------- CSR build ----------
__global__ __launch_bounds__(256) void hist_k(const int* __restrict__ dst, int* __restrict__ cnt, int E){
    int i = blockIdx.x*256 + threadIdx.x;
    if (i < E) atomicAdd(&cnt[dst[i]], 1);
}
__global__ __launch_bounds__(1024) void scan_k(const int* __restrict__ cnt, int* __restrict__ row_off,
                                               float* __restrict__ dinv){
    __shared__ int tot[1024];
    int t = threadIdx.x;
    const int CH = 20;
    int base = t*CH;
    int loc[CH]; int s = 0;
    #pragma unroll
    for (int i = 0; i < CH; ++i){
        int v = (base+i < NN) ? cnt[base+i] : 0;
        loc[i] = s; s += v;
    }
    tot[t] = s; __syncthreads();
    for (int off = 1; off < 1024; off <<= 1){
        int v = (t >= off) ? tot[t-off] : 0;
        __syncthreads();
        tot[t] += v;
        __syncthreads();
    }
    int pre = (t == 0) ? 0 : tot[t-1];
    #pragma unroll
    for (int i = 0; i < CH; ++i)
        if (base+i < NN){
            row_off[base+i] = pre + loc[i];
            dinv[base+i] = rsqrtf((float)cnt[base+i] + 1.f);
        }
    if (t == 1023) row_off[NN] = tot[1023];
}
__global__ __launch_bounds__(256) void scatter_k(const int* __restrict__ src, const int* __restrict__ dst,
        const int* __restrict__ row_off, int* __restrict__ cursor, int* __restrict__ src_sorted, int E){
    int i = blockIdx.x*256 + threadIdx.x;
    if (i >= E) return;
    int d = dst[i];
    int pos = row_off[d] + atomicAdd(&cursor[d], 1);
    src_sorted[pos] = src[i];
}

// ---------- fp16 MFMA GEMM (BN=64 fixed): C[M,N] = A[M,K] @ Bt[N,K]^T ----------
// BM=128, BK=64, 4 waves (2x2). Double-buffered LDS + named-reg prefetch (r11 spill
// lesson: no arrays/lambdas). XOR swizzle (16B chunks, chunk^=row&7) store+read.
// EPI: 0 = store f16 C; 2 = logit atomics (full K); 3 = attention-dot split store.
template<int EPI, bool A_F32, bool RELU, bool HAS_BIAS, int MINW>
__global__ __launch_bounds__(256, MINW) void gemm_f16_k(
        const void* __restrict__ Av, const f16* __restrict__ Bt,
        const float* __restrict__ bias, void* __restrict__ C,
        float* __restrict__ as_out, float* __restrict__ ad_out,
        const float* __restrict__ Wh2, float* __restrict__ logit,
        int M, int N, int K)
{
    constexpr int NJ = 2;                 // WN=32
    __shared__ __align__(16) f16 As[2][128*64];
    __shared__ __align__(16) f16 Bs[2][64*64];
    const int tid  = threadIdx.x;
    const int lane = tid & 63;
    const int wave = tid >> 6;
    const int wm = (wave >> 1) * 64, wn = (wave & 1) * 32;
    const int l15 = lane & 15, quad = lane >> 4;
    const int m0 = blockIdx.y * 128, n0 = blockIdx.x * 64;

    const int rs = tid >> 3;
    const int ce = (tid & 7) * 8;
    const int swst = ((rs & 7) << 3);
    const int swrd = ((l15 & 7) << 3);
    const f16*  Ah = (const f16*)Av;
    const float* Af = (const float*)Av;

    uint4 ra0, ra1, ra2, ra3, rb0, rb1;
    float4 rf00, rf01, rf10, rf11, rf20, rf21, rf30, rf31;

#define GEMM_ISSUE(k0)                                                                    \
    if (A_F32){                                                                           \
        int g0 = m0 + rs, g1 = g0 + 32, g2 = g0 + 64, g3 = g0 + 96;                       \
        if (g0 < M){ rf00 = *(const float4*)(Af + (size_t)g0*K + (k0) + ce);              \
                     rf01 = *(const float4*)(Af + (size_t)g0*K + (k0) + ce + 4); }        \
        else { rf00 = make_float4(0,0,0,0); rf01 = make_float4(0,0,0,0); }                \
        if (g1 < M){ rf10 = *(const float4*)(Af + (size_t)g1*K + (k0) + ce);              \
                     rf11 = *(const float4*)(Af + (size_t)g1*K + (k0) + ce + 4); }        \
        else { rf10 = make_float4(0,0,0,0); rf11 = make_float4(0,0,0,0); }                \
        if (g2 < M){ rf20 = *(const float4*)(Af + (size_t)g2*K + (k0) + ce);              \
                     rf21 = *(const float4*)(Af + (size_t)g2*K + (k0) + ce + 4); }        \
        else { rf20 = make_float4(0,0,0,0); rf21 = make_float4(0,0,0,0); }                \
        if (g3 < M){ rf30 = *(const float4*)(Af + (size_t)g3*K + (k0) + ce);              \
                     rf31 = *(const float4*)(Af + (size_t)g3*K + (k0) + ce + 4); }        \
        else { rf30 = make_float4(0,0,0,0); rf31 = make_float4(0,0,0,0); }                \
    } else {                                                                              \
        ra0 = *(const uint4*)(Ah + (size_t)(m0 + rs      )*K + (k0) + ce);                \
        ra1 = *(const uint4*)(Ah + (size_t)(m0 + rs + 32 )*K + (k0) + ce);                \
        ra2 = *(const uint4*)(Ah + (size_t)(m0 + rs + 64 )*K + (k0) + ce);                \
        ra3 = *(const uint4*)(Ah + (size_t)(m0 + rs + 96 )*K + (k0) + ce);                \
    }                                                                                     \
    rb0 = *(const uint4*)(Bt + (size_t)(n0 + rs     )*K + (k0) + ce);                     \
    rb1 = *(const uint4*)(Bt + (size_t)(n0 + rs + 32)*K + (k0) + ce);

#define GEMM_CVT(hv, lo, hi)                                                              \
    { hv[0]=(f16)lo.x; hv[1]=(f16)lo.y; hv[2]=(f16)lo.z; hv[3]=(f16)lo.w;                 \
      hv[4]=(f16)hi.x; hv[5]=(f16)hi.y; hv[6]=(f16)hi.z; hv[7]=(f16)hi.w; }

#define GEMM_WRITE(buf)                                                                   \
    if (A_F32){                                                                           \
        f16x8v h0, h1, h2, h3;                                                            \
        GEMM_CVT(h0, rf00, rf01) GEMM_CVT(h1, rf10, rf11)                                 \
        GEMM_CVT(h2, rf20, rf21) GEMM_CVT(h3, rf30, rf31)                                 \
        *(f16x8v*)&As[buf][(rs     )*64 + (ce ^ swst)] = h0;                              \
        *(f16x8v*)&As[buf][(rs + 32)*64 + (ce ^ swst)] = h1;                              \
        *(f16x8v*)&As[buf][(rs + 64)*64 + (ce ^ swst)] = h2;                              \
        *(f16x8v*)&As[buf][(rs + 96)*64 + (ce ^ swst)] = h3;                              \
    } else {                                                                              \
        *(uint4*)&As[buf][(rs     )*64 + (ce ^ swst)] = ra0;                              \
        *(uint4*)&As[buf][(rs + 32)*64 + (ce ^ swst)] = ra1;                              \
        *(uint4*)&As[buf][(rs + 64)*64 + (ce ^ swst)] = ra2;                              \
        *(uint4*)&As[buf][(rs + 96)*64 + (ce ^ swst)] = ra3;                              \
    }                                                                                     \
    *(uint4*)&Bs[buf][(rs     )*64 + (ce ^ swst)] = rb0;                                  \
    *(uint4*)&Bs[buf][(rs + 32)*64 + (ce ^ swst)] = rb1;

    GEMM_ISSUE(0)
    GEMM_WRITE(0)
    __syncthreads();

    f32x4 acc[4][NJ] = {};
    int cur = 0;
    for (int k0 = 64; k0 <= K; k0 += 64){
        const bool more = (k0 < K);
        if (more) { GEMM_ISSUE(k0) }
        #pragma unroll
        for (int ks = 0; ks < 2; ++ks){
            f16x8v af[4], bf[NJ];
            const int rc = (ks*32 + quad*8) ^ swrd;
            #pragma unroll
            for (int i = 0; i < 4; ++i)
                af[i] = *(const f16x8v*)&As[cur][(wm + i*16 + l15)*64 + rc];
            #pragma unroll
            for (int j = 0; j < NJ; ++j)
                bf[j] = *(const f16x8v*)&Bs[cur][(wn + j*16 + l15)*64 + rc];
            #pragma unroll
            for (int i = 0; i < 4; ++i)
                #pragma unroll
                for (int j = 0; j < NJ; ++j)
                    acc[i][j] = __builtin_amdgcn_mfma_f32_16x16x32_f16(af[i], bf[j], acc[i][j], 0, 0, 0);
        }
        if (more) { GEMM_WRITE(cur ^ 1) }
        __syncthreads();
        cur ^= 1;
    }
#undef GEMM_ISSUE
#undef GEMM_CVT
#undef GEMM_WRITE

    if (EPI == 2){
        float b4[NJ], w4[NJ];
        #pragma unroll
        for (int j = 0; j < NJ; ++j){
            int cg = n0 + wn + j*16 + l15;
            b4[j] = bias[cg]; w4[j] = Wh2[cg];
        }
        #pragma unroll
        for (int i = 0; i < 4; ++i)
            #pragma unroll
            for (int r = 0; r < 4; ++r){
                float ps = 0.f;
                #pragma unroll
                for (int j = 0; j < NJ; ++j){
                    float v = fmaxf(acc[i][j][r] + b4[j], 0.f);
                    ps = fmaf(v, w4[j], ps);
                }
                ps += __shfl_xor(ps, 1, 64); ps += __shfl_xor(ps, 2, 64);
                ps += __shfl_xor(ps, 4, 64); ps += __shfl_xor(ps, 8, 64);
                if (l15 == 0){
                    int row = m0 + wm + i*16 + quad*4 + r;
                    if (row < M) unsafeAtomicAdd(&logit[row], ps);
                }
            }
        return;
    }

    if (EPI == 3){
        #pragma unroll
        for (int i = 0; i < 4; ++i){
            int rb2 = m0 + wm + i*16 + quad*4;
            #pragma unroll
            for (int j = 0; j < NJ; ++j){
                int col = n0 + wn + j*16 + l15;
                if (col >= 16) continue;
                #pragma unroll
                for (int r = 0; r < 4; ++r){
                    int row = rb2 + r;
                    if (row >= M) continue;
                    float v = acc[i][j][r];
                    if (col < 8) as_out[row*8 + col] = v;
                    else         ad_out[row*8 + col - 8] = v;
                }
            }
        }
        return;
    }

    // store C (f16)
    #pragma unroll
    for (int i = 0; i < 4; ++i){
        int rb2 = m0 + wm + i*16 + quad*4;
        #pragma unroll
        for (int j = 0; j < NJ; ++j){
            int col = n0 + wn + j*16 + l15;
            float bv = HAS_BIAS ? bias[col] : 0.f;
            #pragma unroll
            for (int r = 0; r < 4; ++r){
                int row = rb2 + r;
                if (row >= M) continue;
                float v = acc[i][j][r] + bv;
                if (RELU) v = fmaxf(v, 0.f);
                ((f16*)C)[(size_t)row*N + col] = (f16)v;
            }
        }
    }
}

// ---------- GCN aggregation (1 node/wave, 4-edge unroll — r12 verified form) ----------
template<int F>   // 256 or 128
__global__ __launch_bounds__(256) void gcn_agg_f16_k(const f16* __restrict__ h, const int* __restrict__ row_off,
        const int* __restrict__ srcs, const float* __restrict__ dinv, const float* __restrict__ bias,
        f16* __restrict__ out)
{
    int wv = (blockIdx.x*256 + threadIdx.x) >> 6;
    int lane = threadIdx.x & 63;
    if (wv >= NN) return;
    float di = dinv[wv];
    int p = row_off[wv], r1 = row_off[wv+1];
    if (F == 256){
        f16x4v v = *(const f16x4v*)(h + (size_t)wv*256 + lane*4);
        float c = di*di;
        float a0 = (float)v[0]*c, a1 = (float)v[1]*c, a2 = (float)v[2]*c, a3 = (float)v[3]*c;
        for (; p+4 <= r1; p += 4){
            int s0 = srcs[p], s1 = srcs[p+1], s2 = srcs[p+2], s3 = srcs[p+3];
            float c0 = dinv[s0]*di, c1 = dinv[s1]*di, c2 = dinv[s2]*di, c3 = dinv[s3]*di;
            f16x4v u0 = *(const f16x4v*)(h + (size_t)s0*256 + lane*4);
            f16x4v u1 = *(const f16x4v*)(h + (size_t)s1*256 + lane*4);
            f16x4v u2 = *(const f16x4v*)(h + (size_t)s2*256 + lane*4);
            f16x4v u3 = *(const f16x4v*)(h + (size_t)s3*256 + lane*4);
            a0 = fmaf((float)u3[0], c3, fmaf((float)u2[0], c2, fmaf((float)u1[0], c1, fmaf((float)u0[0], c0, a0))));
            a1 = fmaf((float)u3[1], c3, fmaf((float)u2[1], c2, fmaf((float)u1[1], c1, fmaf((float)u0[1], c0, a1))));
            a2 = fmaf((float)u3[2], c3, fmaf((float)u2[2], c2, fmaf((float)u1[2], c1, fmaf((float)u0[2], c0, a2))));
            a3 = fmaf((float)u3[3], c3, fmaf((float)u2[3], c2, fmaf((float)u1[3], c1, fmaf((float)u0[3], c0, a3))));
        }
        for (; p < r1; ++p){
            int s0 = srcs[p];
            float c0 = dinv[s0]*di;
            f16x4v u0 = *(const f16x4v*)(h + (size_t)s0*256 + lane*4);
            a0 = fmaf((float)u0[0], c0, a0); a1 = fmaf((float)u0[1], c0, a1);
            a2 = fmaf((float)u0[2], c0, a2); a3 = fmaf((float)u0[3], c0, a3);
        }
        float4 bv = *(const float4*)(bias + lane*4);
        f16x4v o;
        o[0] = (f16)fmaxf(a0 + bv.x, 0.f); o[1] = (f16)fmaxf(a1 + bv.y, 0.f);
        o[2] = (f16)fmaxf(a2 + bv.z, 0.f); o[3] = (f16)fmaxf(a3 + bv.w, 0.f);
        *(f16x4v*)(out + (size_t)wv*256 + lane*4) = o;
    } else {
        f16x2 v = *(const f16x2*)(h + (size_t)wv*128 + lane*2);
        float c = di*di;
        float a0 = (float)v[0]*c, a1 = (float)v[1]*c;
        for (; p+4 <= r1; p += 4){
            int s0 = srcs[p], s1 = srcs[p+1], s2 = srcs[p+2], s3 = srcs[p+3];
            float c0 = dinv[s0]*di, c1 = dinv[s1]*di, c2 = dinv[s2]*di, c3 = dinv[s3]*di;
            f16x2 u0 = *(const f16x2*)(h + (size_t)s0*128 + lane*2);
            f16x2 u1 = *(const f16x2*)(h + (size_t)s1*128 + lane*2);
            f16x2 u2 = *(const f16x2*)(h + (size_t)s2*128 + lane*2);
            f16x2 u3 = *(const f16x2*)(h + (size_t)s3*128 + lane*2);
            a0 = fmaf((float)u3[0], c3, fmaf((float)u2[0], c2, fmaf((float)u1[0], c1, fmaf((float)u0[0], c0, a0))));
            a1 = fmaf((float)u3[1], c3, fmaf((float)u2[1], c2, fmaf((float)u1[1], c1, fmaf((float)u0[1], c0, a1))));
        }
        for (; p < r1; ++p){
            int s0 = srcs[p];
            float c0 = dinv[s0]*di;
            f16x2 u0 = *(const f16x2*)(h + (size_t)s0*128 + lane*2);
            a0 = fmaf((float)u0[0], c0, a0); a1 = fmaf((float)u0[1], c0, a1);
        }
        float2 bv = *(const float2*)(bias + lane*2);
        f16x2 o;
        o[0] = (f16)fmaxf(a0 + bv.x, 0.f); o[1] = (f16)fmaxf(a1 + bv.y, 0.f);
        *(f16x2*)(out + (size_t)wv*128 + lane*2) = o;
    }
}

// ---------- GAT softmax over CSR (thread per (node,head), __expf) ----------
__global__ __launch_bounds__(256) void gat_soft_k(const int* __restrict__ row_off, const int* __restrict__ srcs,
        const float* __restrict__ a_s, const float* __restrict__ a_d,
        float* __restrict__ ex_sorted, float* __restrict__ alpha_self, float* __restrict__ inv_den)
{
    int t = blockIdx.x*256 + threadIdx.x;
    if (t >= NN*HEADS) return;
    int d = t >> 3, h = t & 7;
    float ad = a_d[t];
    float eself = lrelu(a_s[t] + ad);
    float m = eself;
    int r0 = row_off[d], r1 = row_off[d+1];
    for (int p = r0; p < r1; ++p){
        int s = srcs[p];
        m = fmaxf(m, lrelu(a_s[s*HEADS + h] + ad));
    }
    float den = __expf(eself - m);
    for (int p = r0; p < r1; ++p){
        int s = srcs[p];
        float x = __expf(lrelu(a_s[s*HEADS + h] + ad) - m);
        ex_sorted[(size_t)p*HEADS + h] = x;
        den += x;
    }
    float id = 1.f / den;
    alpha_self[t] = __expf(eself - m) * id;
    inv_den[t]    = id;
}

// ---------- GAT aggregation in fG-space (r12 verified form: 1 node/wave, 2-edge unroll) ----------
__global__ __launch_bounds__(256) void agg_k(const f16* __restrict__ fG, const int* __restrict__ row_off,
        const int* __restrict__ srcs, const float* __restrict__ exs, const float* __restrict__ aself,
        const float* __restrict__ idn, f16* __restrict__ agg)
{
    int wv = (blockIdx.x*256 + threadIdx.x) >> 6;
    int lane = threadIdx.x & 63;
    if (wv >= NN) return;
    f16x2 v = *(const f16x2*)(fG + (size_t)wv*128 + lane*2);
    float v0 = (float)v[0], v1 = (float)v[1];
    float id[8], acc0[8], acc1[8];
    #pragma unroll
    for (int h = 0; h < 8; ++h){
        float as = aself[wv*8 + h];
        acc0[h] = v0*as; acc1[h] = v1*as;
        id[h] = idn[wv*8 + h];
    }
    int p = row_off[wv], r1 = row_off[wv+1];
    for (; p+2 <= r1; p += 2){
        int s0 = srcs[p], s1 = srcs[p+1];
        f16x2 u0 = *(const f16x2*)(fG + (size_t)s0*128 + lane*2);
        f16x2 u1 = *(const f16x2*)(fG + (size_t)s1*128 + lane*2);
        float4 ea = *(const float4*)(exs + (size_t)p*8);
        float4 eb = *(const float4*)(exs + (size_t)p*8 + 4);
        float4 fa = *(const float4*)(exs + (size_t)(p+1)*8);
        float4 fb = *(const float4*)(exs + (size_t)(p+1)*8 + 4);
        float u00=(float)u0[0], u01=(float)u0[1], u10=(float)u1[0], u11=(float)u1[1];
        float e0[8] = {ea.x,ea.y,ea.z,ea.w,eb.x,eb.y,eb.z,eb.w};
        float e1[8] = {fa.x,fa.y,fa.z,fa.w,fb.x,fb.y,fb.z,fb.w};
        #pragma unroll
        for (int h = 0; h < 8; ++h){
            float al0 = e0[h]*id[h], al1 = e1[h]*id[h];
            acc0[h] = fmaf(u10, al1, fmaf(u00, al0, acc0[h]));
            acc1[h] = fmaf(u11, al1, fmaf(u01, al0, acc1[h]));
        }
    }
    for (; p < r1; ++p){
        int s0 = srcs[p];
        f16x2 u0 = *(const f16x2*)(fG + (size_t)s0*128 + lane*2);
        float4 ea = *(const float4*)(exs + (size_t)p*8);
        float4 eb = *(const float4*)(exs + (size_t)p*8 + 4);
        float u00=(float)u0[0], u01=(float)u0[1];
        float e0[8] = {ea.x,ea.y,ea.z,ea.w,eb.x,eb.y,eb.z,eb.w};
        #pragma unroll
        for (int h = 0; h < 8; ++h){
            float al0 = e0[h]*id[h];
            acc0[h] = fmaf(u00, al0, acc0[h]);
            acc1[h] = fmaf(u01, al0, acc1[h]);
        }
    }
    #pragma unroll
    for (int h = 0; h < 8; ++h){
        f16x2 o; o[0] = (f16)acc0[h]; o[1] = (f16)acc1[h];
        *(f16x2*)(agg + (size_t)wv*1024 + h*128 + lane*2) = o;
    }
}

// ---------- head: sigmoid + global exp-sum (no max pass needed: w in (0,1)) ----------
__global__ __launch_bounds__(256) void head_sum_k(const float* __restrict__ logit, const float* __restrict__ bh2,
                                                  float* __restrict__ w, float* __restrict__ red){
    __shared__ float sm[256];
    int i = blockIdx.x*256 + threadIdx.x;
    float v = 0.f;
    if (i < NN){
        float s = 1.f / (1.f + expf(-(logit[i] + bh2[0])));
        w[i] = s;
        v = expf(s);
    }
    sm[threadIdx.x] = v; __syncthreads();
    for (int off = 128; off; off >>= 1){
        if (threadIdx.x < off) sm[threadIdx.x] += sm[threadIdx.x+off];
        __syncthreads();
    }
    if (!threadIdx.x) unsafeAtomicAdd(&red[0], sm[0]);
}
__global__ __launch_bounds__(256) void final_k(const float* __restrict__ w, const float* __restrict__ red,
                                               float* __restrict__ out){
    int i = blockIdx.x*256 + threadIdx.x;
    if (i >= NN) return;
    out[i] = expf(w[i]) / red[0];
}

// ---------- launch ----------
extern "C" void kernel_launch(void* const* d_in, const int* in_sizes, int n_in,
                              void* d_out, int out_size, void* d_ws, size_t ws_size,
                              hipStream_t stream) {
    const float* x   = (const float*)d_in[0];
    const int*   ei  = (const int*)  d_in[1];
    const float* W1  = (const float*)d_in[2];
    const float* b1  = (const float*)d_in[3];
    const float* W2  = (const float*)d_in[4];
    const float* b2  = (const float*)d_in[5];
    const float* W3  = (const float*)d_in[6];
    const float* b3  = (const float*)d_in[7];
    const float* Wg  = (const float*)d_in[8];
    const float* att_src = (const float*)d_in[9];
    const float* att_dst = (const float*)d_in[10];
    const float* bg  = (const float*)d_in[11];
    const float* Wh1 = (const float*)d_in[12];
    const float* bh1 = (const float*)d_in[13];
    const float* Wh2 = (const float*)d_in[14];
    const float* bh2 = (const float*)d_in[15];
    float* out = (float*)d_out;

    const int E = in_sizes[1] / 2;
    const int* src = ei;
    const int* dst = ei + E;

    float* ws = (float*)d_ws;
    size_t o = 0;
    auto alloc = [&](size_t nfloats){ float* p = ws + o; o += (nfloats + 3) & ~(size_t)3; return p; };
    // zero region: cnt, cursor, logit, red contiguous
    int* cnt    = (int*)alloc(NN);
    int* cursor = (int*)alloc(NN);
    float* logit= alloc(NN);
    float* red  = alloc(8);
    const int ZERO_N = 3*NN + 8;

    f16* wt1   = (f16*)alloc(65536/2);
    f16* wt2   = (f16*)alloc(65536/2);
    f16* wt3   = (f16*)alloc(32768/2);
    f16* wc_t  = (f16*)alloc(262144/2);          // [256][1024] f16
    f16* wasT  = (f16*)alloc(8192/2);            // [64][128] f16, rows 16+ zero
    float* biasc = alloc(256);
    f16* fH    = (f16*)alloc((size_t)M_PAD*256/2);
    f16* fG    = (f16*)alloc((size_t)M_PAD*256/2);
    f16* agg   = (f16*)alloc((size_t)M_PAD*1024/2);
    float* dinv = alloc(NN);
    float* a_s  = alloc((size_t)NN*HEADS);
    float* a_d  = alloc((size_t)NN*HEADS);
    float* aself= alloc((size_t)NN*HEADS);
    float* idn  = alloc((size_t)NN*HEADS);
    float* exs  = alloc((size_t)E*HEADS);
    float* wsig = alloc(NN);
    int* row_off= (int*)alloc(NN+1);
    int* src_srt= (int*)alloc(E);

    const int nb  = (NN + 255)/256;
    const int eb  = (E + 255)/256;
    const int nwb = (NN + 3)/4;    // 1 node/wave, 4 waves/block
    const dim3 blk(256);
    const int MT = M_PAD/128;   // 157

    // init (zero + weight cvt + wasT), Wc fold, CSR, dinv
    const int INIT_T = ZERO_N + 65536*2 + 32768 + 8192;
    init_k<<<(INIT_T + 255)/256, blk, 0, stream>>>(cnt, ZERO_N, W1, W2, W3, Wg, att_src, att_dst,
                                                   wt1, wt2, wt3, wasT);
    wc_k<<<256, blk, 0, stream>>>(Wg, Wh1, bg, bh1, wc_t, biasc);
    hist_k<<<eb, blk, 0, stream>>>(dst, cnt, E);
    scan_k<<<1, 1024, 0, stream>>>(cnt, row_off, dinv);
    scatter_k<<<eb, blk, 0, stream>>>(src, dst, row_off, cursor, src_srt, E);

    // GCN 1: A = x (fp32, read directly)  [4x157 blocks, dbuf prefetch]
    gemm_f16_k<0,true,false,false,3><<<dim3(4, MT), blk, 0, stream>>>(
        x, wt1, nullptr, fH, nullptr, nullptr, nullptr, nullptr, NN, 256, 256);
    gcn_agg_f16_k<256><<<nwb, blk, 0, stream>>>(fH, row_off, src_srt, dinv, b1, fG);
    // GCN 2
    gemm_f16_k<0,false,false,false,3><<<dim3(4, MT), blk, 0, stream>>>(
        fG, wt2, nullptr, fH, nullptr, nullptr, nullptr, nullptr, NN, 256, 256);
    gcn_agg_f16_k<256><<<nwb, blk, 0, stream>>>(fH, row_off, src_srt, dinv, b2, fG);
    // GCN 3 (N=128)
    gemm_f16_k<0,false,false,false,3><<<dim3(2, MT), blk, 0, stream>>>(
        fG, wt3, nullptr, fH, nullptr, nullptr, nullptr, nullptr, NN, 128, 256);
    gcn_agg_f16_k<128><<<nwb, blk, 0, stream>>>(fH, row_off, src_srt, dinv, b3, fG);

    // GAT attention dots: a_sd = fG @ wasT^T via MFMA (EPI=3), M=20000, N=64(16 used), K=128
    gemm_f16_k<3,false,false,false,3><<<dim3(1, MT), blk, 0, stream>>>(
        fG, wasT, nullptr, nullptr, a_s, a_d, nullptr, nullptr, NN, 64, 128);
    // split softmax (exp once per (node,head) thread) + aggregation (reads exs weights)
    gat_soft_k<<<(NN*HEADS)/256, blk, 0, stream>>>(row_off, src_srt, a_s, a_d, exs, aself, idn);
    agg_k<<<nwb, blk, 0, stream>>>(fG, row_off, src_srt, exs, aself, idn, agg);

    // head: z = relu(agg @ Wc + biasc), logit = z @ Wh2  [EPI=2: 628 blocks, full K=1024]
    gemm_f16_k<2,false,true,true,3><<<dim3(4, MT), blk, 0, stream>>>(
        agg, wc_t, biasc, nullptr, nullptr, nullptr, Wh2, logit, NN, 256, 1024);

    // sigmoid + global softmax (no max pass: w bounded in (0,1))
    head_sum_k<<<nb, blk, 0, stream>>>(logit, bh2, wsig, red);
    final_k<<<nb, blk, 0, stream>>>(wsig, red, out);
}

// Round 16
// 331.631 us; speedup vs baseline: 1.0159x; 1.0071x over previous
//
#include <hip/hip_runtime.h>
#include <math.h>

#define NN 20000
#define HEADS 8
#define M_PAD 20096   // 157 * 128

typedef _Float16 f16;
typedef f16 f16x2  __attribute__((ext_vector_type(2)));
typedef f16 f16x4v __attribute__((ext_vector_type(4)));
typedef f16 f16x8v __attribute__((ext_vector_type(8)));
typedef float f32x4 __attribute__((ext_vector_type(4)));

// ---------- helpers ----------
__device__ __forceinline__ float lrelu(float x){ return x > 0.f ? x : 0.2f*x; }

// ---------- merged init + Wc fold (independent work, block-range dispatch) ----------
// blocks [0, init_blocks): zero scratch + weight cvt fp32[K][N] -> f16[N][K] + wasT.
// blocks [init_blocks, init_blocks+256): wc_t[j][k] = blockdiag(Wg)@Wh1 fold, biasc.
// Branch is block-uniform -> wc path's __syncthreads is safe.
__global__ __launch_bounds__(256) void init_wc_k(int init_blocks, int* __restrict__ zbase, int zn,
        const float* __restrict__ W1, const float* __restrict__ W2, const float* __restrict__ W3,
        const float* __restrict__ Wg, const float* __restrict__ att_src, const float* __restrict__ att_dst,
        const float* __restrict__ Wh1, const float* __restrict__ bg, const float* __restrict__ bh1,
        f16* __restrict__ wt1, f16* __restrict__ wt2, f16* __restrict__ wt3,
        f16* __restrict__ wasT, f16* __restrict__ wc_t, float* __restrict__ biasc)
{
    __shared__ float col[1024];
    __shared__ float red[256];
    if ((int)blockIdx.x >= init_blocks){
        const int j = blockIdx.x - init_blocks, t = threadIdx.x;
        float bsum = 0.f;
        #pragma unroll
        for (int i = 0; i < 4; ++i){
            int kk = i*256 + t;
            float v = Wh1[(size_t)kk*256 + j];
            col[kk] = v;
            bsum = fmaf(bg[kk], v, bsum);
        }
        red[t] = bsum; __syncthreads();
        for (int off = 128; off; off >>= 1){
            if (t < off) red[t] += red[t+off];
            __syncthreads();
        }
        if (!t) biasc[j] = red[0] + bh1[j];
        #pragma unroll
        for (int i = 0; i < 4; ++i){
            int k = i*256 + t;
            int h = k >> 7, kk = k & 127;
            const float* wg = Wg + (size_t)kk*1024 + h*128;
            const float* cl = col + h*128;
            float s = 0.f;
            for (int c = 0; c < 128; c += 4){
                float4 wv = *(const float4*)(wg + c);
                s = fmaf(wv.x, cl[c],   s);
                s = fmaf(wv.y, cl[c+1], s);
                s = fmaf(wv.z, cl[c+2], s);
                s = fmaf(wv.w, cl[c+3], s);
            }
            wc_t[(size_t)j*1024 + k] = (f16)s;
        }
        return;
    }
    int t = blockIdx.x*256 + threadIdx.x;
    if (t < zn){ zbase[t] = 0; return; }
    t -= zn;
    if (t < 65536){ int k = t >> 8, n = t & 255; wt1[n*256 + k] = (f16)W1[t]; return; }
    t -= 65536;
    if (t < 65536){ int k = t >> 8, n = t & 255; wt2[n*256 + k] = (f16)W2[t]; return; }
    t -= 65536;
    if (t < 32768){ int k = t >> 7, n = t & 127; wt3[n*256 + k] = (f16)W3[t]; return; }
    t -= 32768;
    if (t < 8192){
        int r = t >> 7, k = t & 127;
        float s = 0.f;
        if (r < 16){
            const float* att = (r < 8) ? att_src : att_dst;
            int h = r & 7;
            const float* wg = Wg + (size_t)k*1024 + h*128;
            const float* at = att + h*128;
            for (int c = 0; c < 128; ++c) s = fmaf(wg[c], at[c], s);
        }
        wasT[r*128 + k] = (f16)s;
    }
}

// ---------- CSR build ----------
__global__ __launch_bounds__(256) void hist_k(const int* __restrict__ dst, int* __restrict__ cnt, int E){
    int i = blockIdx.x*256 + threadIdx.x;
    if (i < E) atomicAdd(&cnt[dst[i]], 1);
}
__global__ __launch_bounds__(1024) void scan_k(const int* __restrict__ cnt, int* __restrict__ row_off,
                                               float* __restrict__ dinv){
    __shared__ int tot[1024];
    int t = threadIdx.x;
    const int CH = 20;
    int base = t*CH;
    int loc[CH]; int s = 0;
    #pragma unroll
    for (int i = 0; i < CH; ++i){
        int v = (base+i < NN) ? cnt[base+i] : 0;
        loc[i] = s; s += v;
    }
    tot[t] = s; __syncthreads();
    for (int off = 1; off < 1024; off <<= 1){
        int v = (t >= off) ? tot[t-off] : 0;
        __syncthreads();
        tot[t] += v;
        __syncthreads();
    }
    int pre = (t == 0) ? 0 : tot[t-1];
    #pragma unroll
    for (int i = 0; i < CH; ++i)
        if (base+i < NN){
            row_off[base+i] = pre + loc[i];
            dinv[base+i] = rsqrtf((float)cnt[base+i] + 1.f);
        }
    if (t == 1023) row_off[NN] = tot[1023];
}
__global__ __launch_bounds__(256) void scatter_k(const int* __restrict__ src, const int* __restrict__ dst,
        const int* __restrict__ row_off, int* __restrict__ cursor, int* __restrict__ src_sorted, int E){
    int i = blockIdx.x*256 + threadIdx.x;
    if (i >= E) return;
    int d = dst[i];
    int pos = row_off[d] + atomicAdd(&cursor[d], 1);
    src_sorted[pos] = src[i];
}

// ---------- fp16 MFMA GEMM (BN=64 fixed): C[M,N] = A[M,K] @ Bt[N,K]^T ----------
// BM=128, BK=64, 4 waves (2x2). Double-buffered LDS + named-reg prefetch (r11 spill
// lesson: no arrays/lambdas). XOR swizzle (16B chunks, chunk^=row&7) store+read.
// EPI: 0 = store f16 C; 2 = logit atomics (full K); 3 = attention-dot split store.
template<int EPI, bool A_F32, bool RELU, bool HAS_BIAS, int MINW>
__global__ __launch_bounds__(256, MINW) void gemm_f16_k(
        const void* __restrict__ Av, const f16* __restrict__ Bt,
        const float* __restrict__ bias, void* __restrict__ C,
        float* __restrict__ as_out, float* __restrict__ ad_out,
        const float* __restrict__ Wh2, float* __restrict__ logit,
        int M, int N, int K)
{
    constexpr int NJ = 2;                 // WN=32
    __shared__ __align__(16) f16 As[2][128*64];
    __shared__ __align__(16) f16 Bs[2][64*64];
    const int tid  = threadIdx.x;
    const int lane = tid & 63;
    const int wave = tid >> 6;
    const int wm = (wave >> 1) * 64, wn = (wave & 1) * 32;
    const int l15 = lane & 15, quad = lane >> 4;
    const int m0 = blockIdx.y * 128, n0 = blockIdx.x * 64;

    const int rs = tid >> 3;
    const int ce = (tid & 7) * 8;
    const int swst = ((rs & 7) << 3);
    const int swrd = ((l15 & 7) << 3);
    const f16*  Ah = (const f16*)Av;
    const float* Af = (const float*)Av;

    uint4 ra0, ra1, ra2, ra3, rb0, rb1;
    float4 rf00, rf01, rf10, rf11, rf20, rf21, rf30, rf31;

#define GEMM_ISSUE(k0)                                                                    \
    if (A_F32){                                                                           \
        int g0 = m0 + rs, g1 = g0 + 32, g2 = g0 + 64, g3 = g0 + 96;                       \
        if (g0 < M){ rf00 = *(const float4*)(Af + (size_t)g0*K + (k0) + ce);              \
                     rf01 = *(const float4*)(Af + (size_t)g0*K + (k0) + ce + 4); }        \
        else { rf00 = make_float4(0,0,0,0); rf01 = make_float4(0,0,0,0); }                \
        if (g1 < M){ rf10 = *(const float4*)(Af + (size_t)g1*K + (k0) + ce);              \
                     rf11 = *(const float4*)(Af + (size_t)g1*K + (k0) + ce + 4); }        \
        else { rf10 = make_float4(0,0,0,0); rf11 = make_float4(0,0,0,0); }                \
        if (g2 < M){ rf20 = *(const float4*)(Af + (size_t)g2*K + (k0) + ce);              \
                     rf21 = *(const float4*)(Af + (size_t)g2*K + (k0) + ce + 4); }        \
        else { rf20 = make_float4(0,0,0,0); rf21 = make_float4(0,0,0,0); }                \
        if (g3 < M){ rf30 = *(const float4*)(Af + (size_t)g3*K + (k0) + ce);              \
                     rf31 = *(const float4*)(Af + (size_t)g3*K + (k0) + ce + 4); }        \
        else { rf30 = make_float4(0,0,0,0); rf31 = make_float4(0,0,0,0); }                \
    } else {                                                                              \
        ra0 = *(const uint4*)(Ah + (size_t)(m0 + rs      )*K + (k0) + ce);                \
        ra1 = *(const uint4*)(Ah + (size_t)(m0 + rs + 32 )*K + (k0) + ce);                \
        ra2 = *(const uint4*)(Ah + (size_t)(m0 + rs + 64 )*K + (k0) + ce);                \
        ra3 = *(const uint4*)(Ah + (size_t)(m0 + rs + 96 )*K + (k0) + ce);                \
    }                                                                                     \
    rb0 = *(const uint4*)(Bt + (size_t)(n0 + rs     )*K + (k0) + ce);                     \
    rb1 = *(const uint4*)(Bt + (size_t)(n0 + rs + 32)*K + (k0) + ce);

#define GEMM_CVT(hv, lo, hi)                                                              \
    { hv[0]=(f16)lo.x; hv[1]=(f16)lo.y; hv[2]=(f16)lo.z; hv[3]=(f16)lo.w;                 \
      hv[4]=(f16)hi.x; hv[5]=(f16)hi.y; hv[6]=(f16)hi.z; hv[7]=(f16)hi.w; }

#define GEMM_WRITE(buf)                                                                   \
    if (A_F32){                                                                           \
        f16x8v h0, h1, h2, h3;                                                            \
        GEMM_CVT(h0, rf00, rf01) GEMM_CVT(h1, rf10, rf11)                                 \
        GEMM_CVT(h2, rf20, rf21) GEMM_CVT(h3, rf30, rf31)                                 \
        *(f16x8v*)&As[buf][(rs     )*64 + (ce ^ swst)] = h0;                              \
        *(f16x8v*)&As[buf][(rs + 32)*64 + (ce ^ swst)] = h1;                              \
        *(f16x8v*)&As[buf][(rs + 64)*64 + (ce ^ swst)] = h2;                              \
        *(f16x8v*)&As[buf][(rs + 96)*64 + (ce ^ swst)] = h3;                              \
    } else {                                                                              \
        *(uint4*)&As[buf][(rs     )*64 + (ce ^ swst)] = ra0;                              \
        *(uint4*)&As[buf][(rs + 32)*64 + (ce ^ swst)] = ra1;                              \
        *(uint4*)&As[buf][(rs + 64)*64 + (ce ^ swst)] = ra2;                              \
        *(uint4*)&As[buf][(rs + 96)*64 + (ce ^ swst)] = ra3;                              \
    }                                                                                     \
    *(uint4*)&Bs[buf][(rs     )*64 + (ce ^ swst)] = rb0;                                  \
    *(uint4*)&Bs[buf][(rs + 32)*64 + (ce ^ swst)] = rb1;

    GEMM_ISSUE(0)
    GEMM_WRITE(0)
    __syncthreads();

    f32x4 acc[4][NJ] = {};
    int cur = 0;
    for (int k0 = 64; k0 <= K; k0 += 64){
        const bool more = (k0 < K);
        if (more) { GEMM_ISSUE(k0) }
        #pragma unroll
        for (int ks = 0; ks < 2; ++ks){
            f16x8v af[4], bf[NJ];
            const int rc = (ks*32 + quad*8) ^ swrd;
            #pragma unroll
            for (int i = 0; i < 4; ++i)
                af[i] = *(const f16x8v*)&As[cur][(wm + i*16 + l15)*64 + rc];
            #pragma unroll
            for (int j = 0; j < NJ; ++j)
                bf[j] = *(const f16x8v*)&Bs[cur][(wn + j*16 + l15)*64 + rc];
            #pragma unroll
            for (int i = 0; i < 4; ++i)
                #pragma unroll
                for (int j = 0; j < NJ; ++j)
                    acc[i][j] = __builtin_amdgcn_mfma_f32_16x16x32_f16(af[i], bf[j], acc[i][j], 0, 0, 0);
        }
        if (more) { GEMM_WRITE(cur ^ 1) }
        __syncthreads();
        cur ^= 1;
    }
#undef GEMM_ISSUE
#undef GEMM_CVT
#undef GEMM_WRITE

    if (EPI == 2){
        float b4[NJ], w4[NJ];
        #pragma unroll
        for (int j = 0; j < NJ; ++j){
            int cg = n0 + wn + j*16 + l15;
            b4[j] = bias[cg]; w4[j] = Wh2[cg];
        }
        #pragma unroll
        for (int i = 0; i < 4; ++i)
            #pragma unroll
            for (int r = 0; r < 4; ++r){
                float ps = 0.f;
                #pragma unroll
                for (int j = 0; j < NJ; ++j){
                    float v = fmaxf(acc[i][j][r] + b4[j], 0.f);
                    ps = fmaf(v, w4[j], ps);
                }
                ps += __shfl_xor(ps, 1, 64); ps += __shfl_xor(ps, 2, 64);
                ps += __shfl_xor(ps, 4, 64); ps += __shfl_xor(ps, 8, 64);
                if (l15 == 0){
                    int row = m0 + wm + i*16 + quad*4 + r;
                    if (row < M) unsafeAtomicAdd(&logit[row], ps);
                }
            }
        return;
    }

    if (EPI == 3){
        #pragma unroll
        for (int i = 0; i < 4; ++i){
            int rb2 = m0 + wm + i*16 + quad*4;
            #pragma unroll
            for (int j = 0; j < NJ; ++j){
                int col = n0 + wn + j*16 + l15;
                if (col >= 16) continue;
                #pragma unroll
                for (int r = 0; r < 4; ++r){
                    int row = rb2 + r;
                    if (row >= M) continue;
                    float v = acc[i][j][r];
                    if (col < 8) as_out[row*8 + col] = v;
                    else         ad_out[row*8 + col - 8] = v;
                }
            }
        }
        return;
    }

    // store C (f16)
    #pragma unroll
    for (int i = 0; i < 4; ++i){
        int rb2 = m0 + wm + i*16 + quad*4;
        #pragma unroll
        for (int j = 0; j < NJ; ++j){
            int col = n0 + wn + j*16 + l15;
            float bv = HAS_BIAS ? bias[col] : 0.f;
            #pragma unroll
            for (int r = 0; r < 4; ++r){
                int row = rb2 + r;
                if (row >= M) continue;
                float v = acc[i][j][r] + bv;
                if (RELU) v = fmaxf(v, 0.f);
                ((f16*)C)[(size_t)row*N + col] = (f16)v;
            }
        }
    }
}

// ---------- GCN aggregation (1 node/wave, 4-edge unroll — r12 verified form) ----------
template<int F>   // 256 or 128
__global__ __launch_bounds__(256) void gcn_agg_f16_k(const f16* __restrict__ h, const int* __restrict__ row_off,
        const int* __restrict__ srcs, const float* __restrict__ dinv, const float* __restrict__ bias,
        f16* __restrict__ out)
{
    int wv = (blockIdx.x*256 + threadIdx.x) >> 6;
    int lane = threadIdx.x & 63;
    if (wv >= NN) return;
    float di = dinv[wv];
    int p = row_off[wv], r1 = row_off[wv+1];
    if (F == 256){
        f16x4v v = *(const f16x4v*)(h + (size_t)wv*256 + lane*4);
        float c = di*di;
        float a0 = (float)v[0]*c, a1 = (float)v[1]*c, a2 = (float)v[2]*c, a3 = (float)v[3]*c;
        for (; p+4 <= r1; p += 4){
            int s0 = srcs[p], s1 = srcs[p+1], s2 = srcs[p+2], s3 = srcs[p+3];
            float c0 = dinv[s0]*di, c1 = dinv[s1]*di, c2 = dinv[s2]*di, c3 = dinv[s3]*di;
            f16x4v u0 = *(const f16x4v*)(h + (size_t)s0*256 + lane*4);
            f16x4v u1 = *(const f16x4v*)(h + (size_t)s1*256 + lane*4);
            f16x4v u2 = *(const f16x4v*)(h + (size_t)s2*256 + lane*4);
            f16x4v u3 = *(const f16x4v*)(h + (size_t)s3*256 + lane*4);
            a0 = fmaf((float)u3[0], c3, fmaf((float)u2[0], c2, fmaf((float)u1[0], c1, fmaf((float)u0[0], c0, a0))));
            a1 = fmaf((float)u3[1], c3, fmaf((float)u2[1], c2, fmaf((float)u1[1], c1, fmaf((float)u0[1], c0, a1))));
            a2 = fmaf((float)u3[2], c3, fmaf((float)u2[2], c2, fmaf((float)u1[2], c1, fmaf((float)u0[2], c0, a2))));
            a3 = fmaf((float)u3[3], c3, fmaf((float)u2[3], c2, fmaf((float)u1[3], c1, fmaf((float)u0[3], c0, a3))));
        }
        for (; p < r1; ++p){
            int s0 = srcs[p];
            float c0 = dinv[s0]*di;
            f16x4v u0 = *(const f16x4v*)(h + (size_t)s0*256 + lane*4);
            a0 = fmaf((float)u0[0], c0, a0); a1 = fmaf((float)u0[1], c0, a1);
            a2 = fmaf((float)u0[2], c0, a2); a3 = fmaf((float)u0[3], c0, a3);
        }
        float4 bv = *(const float4*)(bias + lane*4);
        f16x4v o;
        o[0] = (f16)fmaxf(a0 + bv.x, 0.f); o[1] = (f16)fmaxf(a1 + bv.y, 0.f);
        o[2] = (f16)fmaxf(a2 + bv.z, 0.f); o[3] = (f16)fmaxf(a3 + bv.w, 0.f);
        *(f16x4v*)(out + (size_t)wv*256 + lane*4) = o;
    } else {
        f16x2 v = *(const f16x2*)(h + (size_t)wv*128 + lane*2);
        float c = di*di;
        float a0 = (float)v[0]*c, a1 = (float)v[1]*c;
        for (; p+4 <= r1; p += 4){
            int s0 = srcs[p], s1 = srcs[p+1], s2 = srcs[p+2], s3 = srcs[p+3];
            float c0 = dinv[s0]*di, c1 = dinv[s1]*di, c2 = dinv[s2]*di, c3 = dinv[s3]*di;
            f16x2 u0 = *(const f16x2*)(h + (size_t)s0*128 + lane*2);
            f16x2 u1 = *(const f16x2*)(h + (size_t)s1*128 + lane*2);
            f16x2 u2 = *(const f16x2*)(h + (size_t)s2*128 + lane*2);
            f16x2 u3 = *(const f16x2*)(h + (size_t)s3*128 + lane*2);
            a0 = fmaf((float)u3[0], c3, fmaf((float)u2[0], c2, fmaf((float)u1[0], c1, fmaf((float)u0[0], c0, a0))));
            a1 = fmaf((float)u3[1], c3, fmaf((float)u2[1], c2, fmaf((float)u1[1], c1, fmaf((float)u0[1], c0, a1))));
        }
        for (; p < r1; ++p){
            int s0 = srcs[p];
            float c0 = dinv[s0]*di;
            f16x2 u0 = *(const f16x2*)(h + (size_t)s0*128 + lane*2);
            a0 = fmaf((float)u0[0], c0, a0); a1 = fmaf((float)u0[1], c0, a1);
        }
        float2 bv = *(const float2*)(bias + lane*2);
        f16x2 o;
        o[0] = (f16)fmaxf(a0 + bv.x, 0.f); o[1] = (f16)fmaxf(a1 + bv.y, 0.f);
        *(f16x2*)(out + (size_t)wv*128 + lane*2) = o;
    }
}

// ---------- GAT softmax over CSR (thread per (node,head), __expf) ----------
__global__ __launch_bounds__(256) void gat_soft_k(const int* __restrict__ row_off, const int* __restrict__ srcs,
        const float* __restrict__ a_s, const float* __restrict__ a_d,
        float* __restrict__ ex_sorted, float* __restrict__ alpha_self, float* __restrict__ inv_den)
{
    int t = blockIdx.x*256 + threadIdx.x;
    if (t >= NN*HEADS) return;
    int d = t >> 3, h = t & 7;
    float ad = a_d[t];
    float eself = lrelu(a_s[t] + ad);
    float m = eself;
    int r0 = row_off[d], r1 = row_off[d+1];
    for (int p = r0; p < r1; ++p){
        int s = srcs[p];
        m = fmaxf(m, lrelu(a_s[s*HEADS + h] + ad));
    }
    float den = __expf(eself - m);
    for (int p = r0; p < r1; ++p){
        int s = srcs[p];
        float x = __expf(lrelu(a_s[s*HEADS + h] + ad) - m);
        ex_sorted[(size_t)p*HEADS + h] = x;
        den += x;
    }
    float id = 1.f / den;
    alpha_self[t] = __expf(eself - m) * id;
    inv_den[t]    = id;
}

// ---------- GAT aggregation in fG-space (r12 verified form: 1 node/wave, 2-edge unroll) ----------
__global__ __launch_bounds__(256) void agg_k(const f16* __restrict__ fG, const int* __restrict__ row_off,
        const int* __restrict__ srcs, const float* __restrict__ exs, const float* __restrict__ aself,
        const float* __restrict__ idn, f16* __restrict__ agg)
{
    int wv = (blockIdx.x*256 + threadIdx.x) >> 6;
    int lane = threadIdx.x & 63;
    if (wv >= NN) return;
    f16x2 v = *(const f16x2*)(fG + (size_t)wv*128 + lane*2);
    float v0 = (float)v[0], v1 = (float)v[1];
    float id[8], acc0[8], acc1[8];
    #pragma unroll
    for (int h = 0; h < 8; ++h){
        float as = aself[wv*8 + h];
        acc0[h] = v0*as; acc1[h] = v1*as;
        id[h] = idn[wv*8 + h];
    }
    int p = row_off[wv], r1 = row_off[wv+1];
    for (; p+2 <= r1; p += 2){
        int s0 = srcs[p], s1 = srcs[p+1];
        f16x2 u0 = *(const f16x2*)(fG + (size_t)s0*128 + lane*2);
        f16x2 u1 = *(const f16x2*)(fG + (size_t)s1*128 + lane*2);
        float4 ea = *(const float4*)(exs + (size_t)p*8);
        float4 eb = *(const float4*)(exs + (size_t)p*8 + 4);
        float4 fa = *(const float4*)(exs + (size_t)(p+1)*8);
        float4 fb = *(const float4*)(exs + (size_t)(p+1)*8 + 4);
        float u00=(float)u0[0], u01=(float)u0[1], u10=(float)u1[0], u11=(float)u1[1];
        float e0[8] = {ea.x,ea.y,ea.z,ea.w,eb.x,eb.y,eb.z,eb.w};
        float e1[8] = {fa.x,fa.y,fa.z,fa.w,fb.x,fb.y,fb.z,fb.w};
        #pragma unroll
        for (int h = 0; h < 8; ++h){
            float al0 = e0[h]*id[h], al1 = e1[h]*id[h];
            acc0[h] = fmaf(u10, al1, fmaf(u00, al0, acc0[h]));
            acc1[h] = fmaf(u11, al1, fmaf(u01, al0, acc1[h]));
        }
    }
    for (; p < r1; ++p){
        int s0 = srcs[p];
        f16x2 u0 = *(const f16x2*)(fG + (size_t)s0*128 + lane*2);
        float4 ea = *(const float4*)(exs + (size_t)p*8);
        float4 eb = *(const float4*)(exs + (size_t)p*8 + 4);
        float u00=(float)u0[0], u01=(float)u0[1];
        float e0[8] = {ea.x,ea.y,ea.z,ea.w,eb.x,eb.y,eb.z,eb.w};
        #pragma unroll
        for (int h = 0; h < 8; ++h){
            float al0 = e0[h]*id[h];
            acc0[h] = fmaf(u00, al0, acc0[h]);
            acc1[h] = fmaf(u01, al0, acc1[h]);
        }
    }
    #pragma unroll
    for (int h = 0; h < 8; ++h){
        f16x2 o; o[0] = (f16)acc0[h]; o[1] = (f16)acc1[h];
        *(f16x2*)(agg + (size_t)wv*1024 + h*128 + lane*2) = o;
    }
}

// ---------- head: sigmoid + global exp-sum (no max pass needed: w in (0,1)) ----------
__global__ __launch_bounds__(256) void head_sum_k(const float* __restrict__ logit, const float* __restrict__ bh2,
                                                  float* __restrict__ w, float* __restrict__ red){
    __shared__ float sm[256];
    int i = blockIdx.x*256 + threadIdx.x;
    float v = 0.f;
    if (i < NN){
        float s = 1.f / (1.f + expf(-(logit[i] + bh2[0])));
        w[i] = s;
        v = expf(s);
    }
    sm[threadIdx.x] = v; __syncthreads();
    for (int off = 128; off; off >>= 1){
        if (threadIdx.x < off) sm[threadIdx.x] += sm[threadIdx.x+off];
        __syncthreads();
    }
    if (!threadIdx.x) unsafeAtomicAdd(&red[0], sm[0]);
}
__global__ __launch_bounds__(256) void final_k(const float* __restrict__ w, const float* __restrict__ red,
                                               float* __restrict__ out){
    int i = blockIdx.x*256 + threadIdx.x;
    if (i >= NN) return;
    out[i] = expf(w[i]) / red[0];
}

// ---------- launch ----------
extern "C" void kernel_launch(void* const* d_in, const int* in_sizes, int n_in,
                              void* d_out, int out_size, void* d_ws, size_t ws_size,
                              hipStream_t stream) {
    const float* x   = (const float*)d_in[0];
    const int*   ei  = (const int*)  d_in[1];
    const float* W1  = (const float*)d_in[2];
    const float* b1  = (const float*)d_in[3];
    const float* W2  = (const float*)d_in[4];
    const float* b2  = (const float*)d_in[5];
    const float* W3  = (const float*)d_in[6];
    const float* b3  = (const float*)d_in[7];
    const float* Wg  = (const float*)d_in[8];
    const float* att_src = (const float*)d_in[9];
    const float* att_dst = (const float*)d_in[10];
    const float* bg  = (const float*)d_in[11];
    const float* Wh1 = (const float*)d_in[12];
    const float* bh1 = (const float*)d_in[13];
    const float* Wh2 = (const float*)d_in[14];
    const float* bh2 = (const float*)d_in[15];
    float* out = (float*)d_out;

    const int E = in_sizes[1] / 2;
    const int* src = ei;
    const int* dst = ei + E;

    float* ws = (float*)d_ws;
    size_t o = 0;
    auto alloc = [&](size_t nfloats){ float* p = ws + o; o += (nfloats + 3) & ~(size_t)3; return p; };
    // zero region: cnt, cursor, logit, red contiguous
    int* cnt    = (int*)alloc(NN);
    int* cursor = (int*)alloc(NN);
    float* logit= alloc(NN);
    float* red  = alloc(8);
    const int ZERO_N = 3*NN + 8;

    f16* wt1   = (f16*)alloc(65536/2);
    f16* wt2   = (f16*)alloc(65536/2);
    f16* wt3   = (f16*)alloc(32768/2);
    f16* wc_t  = (f16*)alloc(262144/2);          // [256][1024] f16
    f16* wasT  = (f16*)alloc(8192/2);            // [64][128] f16, rows 16+ zero
    float* biasc = alloc(256);
    f16* fH    = (f16*)alloc((size_t)M_PAD*256/2);
    f16* fG    = (f16*)alloc((size_t)M_PAD*256/2);
    f16* agg   = (f16*)alloc((size_t)M_PAD*1024/2);
    float* dinv = alloc(NN);
    float* a_s  = alloc((size_t)NN*HEADS);
    float* a_d  = alloc((size_t)NN*HEADS);
    float* aself= alloc((size_t)NN*HEADS);
    float* idn  = alloc((size_t)NN*HEADS);
    float* exs  = alloc((size_t)E*HEADS);
    float* wsig = alloc(NN);
    int* row_off= (int*)alloc(NN+1);
    int* src_srt= (int*)alloc(E);

    const int nb  = (NN + 255)/256;
    const int eb  = (E + 255)/256;
    const int nwb = (NN + 3)/4;    // 1 node/wave, 4 waves/block
    const dim3 blk(256);
    const int MT = M_PAD/128;   // 157

    // merged init (zero + weight cvt + wasT) + Wc fold; then CSR, dinv
    const int INIT_T = ZERO_N + 65536*2 + 32768 + 8192;
    const int INIT_B = (INIT_T + 255)/256;
    init_wc_k<<<INIT_B + 256, blk, 0, stream>>>(INIT_B, cnt, ZERO_N, W1, W2, W3,
                                                Wg, att_src, att_dst, Wh1, bg, bh1,
                                                wt1, wt2, wt3, wasT, wc_t, biasc);
    hist_k<<<eb, blk, 0, stream>>>(dst, cnt, E);
    scan_k<<<1, 1024, 0, stream>>>(cnt, row_off, dinv);
    scatter_k<<<eb, blk, 0, stream>>>(src, dst, row_off, cursor, src_srt, E);

    // GCN 1: A = x (fp32, read directly)  [4x157 blocks, dbuf prefetch]
    gemm_f16_k<0,true,false,false,3><<<dim3(4, MT), blk, 0, stream>>>(
        x, wt1, nullptr, fH, nullptr, nullptr, nullptr, nullptr, NN, 256, 256);
    gcn_agg_f16_k<256><<<nwb, blk, 0, stream>>>(fH, row_off, src_srt, dinv, b1, fG);
    // GCN 2
    gemm_f16_k<0,false,false,false,3><<<dim3(4, MT), blk, 0, stream>>>(
        fG, wt2, nullptr, fH, nullptr, nullptr, nullptr, nullptr, NN, 256, 256);
    gcn_agg_f16_k<256><<<nwb, blk, 0, stream>>>(fH, row_off, src_srt, dinv, b2, fG);
    // GCN 3 (N=128)
    gemm_f16_k<0,false,false,false,3><<<dim3(2, MT), blk, 0, stream>>>(
        fG, wt3, nullptr, fH, nullptr, nullptr, nullptr, nullptr, NN, 128, 256);
    gcn_agg_f16_k<128><<<nwb, blk, 0, stream>>>(fH, row_off, src_srt, dinv, b3, fG);

    // GAT attention dots: a_sd = fG @ wasT^T via MFMA (EPI=3), M=20000, N=64(16 used), K=128
    gemm_f16_k<3,false,false,false,3><<<dim3(1, MT), blk, 0, stream>>>(
        fG, wasT, nullptr, nullptr, a_s, a_d, nullptr, nullptr, NN, 64, 128);
    // split softmax (exp once per (node,head) thread) + aggregation (reads exs weights)
    gat_soft_k<<<(NN*HEADS)/256, blk, 0, stream>>>(row_off, src_srt, a_s, a_d, exs, aself, idn);
    agg_k<<<nwb, blk, 0, stream>>>(fG, row_off, src_srt, exs, aself, idn, agg);

    // head: z = relu(agg @ Wc + biasc), logit = z @ Wh2  [EPI=2: 628 blocks, full K=1024]
    gemm_f16_k<2,false,true,true,3><<<dim3(4, MT), blk, 0, stream>>>(
        agg, wc_t, biasc, nullptr, nullptr, nullptr, Wh2, logit, NN, 256, 1024);

    // sigmoid + global softmax (no max pass: w bounded in (0,1))
    head_sum_k<<<nb, blk, 0, stream>>>(logit, bh2, wsig, red);
    final_k<<<nb, blk, 0, stream>>>(wsig, red, out);
}